// Round 11
// baseline (4110.900 us; speedup 1.0000x reference)
//
#include <hip/hip_runtime.h>

#define B_    4
#define N1_   16384
#define M1_   2048
#define M2_   512
#define KNN_  32
#define PROJ_ 64
#define C1_   128
#define C2_   256
#define PROJ_BLKS_ ((B_ * N1_ * PROJ_) / 512)   // 8192
#define KNN_BLKS_  ((M1_ / 64) * (B_ * 64))     // 8192 (chunk-major order)

__device__ __forceinline__ float sqdist_exact(float px, float py, float pz,
                                              float cx, float cy, float cz) {
    // Must match numpy: ((dx*dx + dy*dy) + dz*dz), no FMA contraction.
    float dx = __fsub_rn(px, cx);
    float dy = __fsub_rn(py, cy);
    float dz = __fsub_rn(pz, cz);
    return __fadd_rn(__fadd_rn(__fmul_rn(dx, dx), __fmul_rn(dy, dy)), __fmul_rn(dz, dz));
}

// ---------------- Morton sort (counting sort on top-10 Morton bits) ----------
// Round-14: r10's x-slab skip barely fired (x-slab spans full y-z extent ->
// box distance == x-gap only; middle slabs never skip). Morton-sorted waves
// own compact 3D regions -> exact AABB ~8x smaller volume -> box-distance
// bound fires earlier and more often. Within-bin order arbitrary (atomics
// race) — harmless: FPS keys carry orig indices (order-independent) and the
// AABB is computed from the actual points each wave owns.
__device__ __forceinline__ unsigned spread3(unsigned v) {
    v &= 0x3FFu;
    v = (v | (v << 16)) & 0x030000FFu;
    v = (v | (v << 8))  & 0x0300F00Fu;
    v = (v | (v << 4))  & 0x030C30C3u;
    v = (v | (v << 2))  & 0x09249249u;
    return v;
}

__global__ void __launch_bounds__(1024)
sortm_kernel(const float* __restrict__ xyz, float* __restrict__ sx,
             float* __restrict__ sy, float* __restrict__ sz,
             unsigned* __restrict__ scid) {
    const int b = blockIdx.x, t = threadIdx.x;
    const int lane = t & 63, w = t >> 6;
    const float* P = xyz + (size_t)b * N1_ * 3;
    __shared__ int hist[1024];
    __shared__ int wsum[16];
    __shared__ float wred[16][6];
    __shared__ float bb[6];

    // ---- phase 1: per-batch min/max of x,y,z
    float mnx = 1e30f, mxx = -1e30f, mny = 1e30f, mxy = -1e30f,
          mnz = 1e30f, mxz = -1e30f;
    for (int j = t; j < N1_; j += 1024) {
        float x = P[j * 3], y = P[j * 3 + 1], z = P[j * 3 + 2];
        mnx = fminf(mnx, x); mxx = fmaxf(mxx, x);
        mny = fminf(mny, y); mxy = fmaxf(mxy, y);
        mnz = fminf(mnz, z); mxz = fmaxf(mxz, z);
    }
    for (int off = 1; off < 64; off <<= 1) {
        mnx = fminf(mnx, __shfl_xor(mnx, off)); mxx = fmaxf(mxx, __shfl_xor(mxx, off));
        mny = fminf(mny, __shfl_xor(mny, off)); mxy = fmaxf(mxy, __shfl_xor(mxy, off));
        mnz = fminf(mnz, __shfl_xor(mnz, off)); mxz = fmaxf(mxz, __shfl_xor(mxz, off));
    }
    if (lane == 0) {
        wred[w][0] = mnx; wred[w][1] = mxx; wred[w][2] = mny;
        wred[w][3] = mxy; wred[w][4] = mnz; wred[w][5] = mxz;
    }
    __syncthreads();
    if (t == 0) {
        float a0 = wred[0][0], a1 = wred[0][1], a2 = wred[0][2],
              a3 = wred[0][3], a4 = wred[0][4], a5 = wred[0][5];
        for (int i = 1; i < 16; ++i) {
            a0 = fminf(a0, wred[i][0]); a1 = fmaxf(a1, wred[i][1]);
            a2 = fminf(a2, wred[i][2]); a3 = fmaxf(a3, wred[i][3]);
            a4 = fminf(a4, wred[i][4]); a5 = fmaxf(a5, wred[i][5]);
        }
        bb[0] = a0; bb[1] = a1; bb[2] = a2; bb[3] = a3; bb[4] = a4; bb[5] = a5;
    }
    hist[t] = 0;
    __syncthreads();
    const float ox = bb[0], oy = bb[2], oz = bb[4];
    const float scx = 1023.0f / fmaxf(bb[1] - bb[0], 1e-20f);
    const float scy = 1023.0f / fmaxf(bb[3] - bb[2], 1e-20f);
    const float scz = 1023.0f / fmaxf(bb[5] - bb[4], 1e-20f);

    // ---- phase 2: histogram of top-10 Morton bits
    for (int j = t; j < N1_; j += 1024) {
        unsigned qx = (unsigned)fminf((P[j * 3 + 0] - ox) * scx, 1023.f);
        unsigned qy = (unsigned)fminf((P[j * 3 + 1] - oy) * scy, 1023.f);
        unsigned qz = (unsigned)fminf((P[j * 3 + 2] - oz) * scz, 1023.f);
        unsigned code = (spread3(qx) << 2) | (spread3(qy) << 1) | spread3(qz);
        atomicAdd(&hist[code >> 20], 1);
    }
    __syncthreads();
    // ---- phase 3: exclusive prefix over 1024 bins
    int v = hist[t];
    int cum = v;
    for (int off = 1; off < 64; off <<= 1) {
        int o = __shfl_up(cum, off);
        if (lane >= off) cum += o;
    }
    if (lane == 63) wsum[w] = cum;
    __syncthreads();
    int wpre = 0;
    for (int i = 0; i < w; ++i) wpre += wsum[i];
    const int excl = cum - v + wpre;
    __syncthreads();
    hist[t] = excl;
    __syncthreads();
    // ---- phase 4: scatter (sorted coords + pre-complemented orig index)
    for (int j = t; j < N1_; j += 1024) {
        float x = P[j * 3], y = P[j * 3 + 1], z = P[j * 3 + 2];
        unsigned qx = (unsigned)fminf((x - ox) * scx, 1023.f);
        unsigned qy = (unsigned)fminf((y - oy) * scy, 1023.f);
        unsigned qz = (unsigned)fminf((z - oz) * scz, 1023.f);
        unsigned code = (spread3(qx) << 2) | (spread3(qy) << 1) | spread3(qz);
        int pos = atomicAdd(&hist[code >> 20], 1);
        size_t o = (size_t)b * N1_ + pos;
        sx[o] = x; sy[o] = y; sz[o] = z; scid[o] = ~(unsigned)j;
    }
}

// ---------------- FPS primitives (proven bit-exact through r10) ---------------
// key = (f32bits(dmin) << 32) | ~origidx : u64 max == max value, tie -> min
// orig index (exactly jnp.argmax first-occurrence; order-independent).
typedef float v2f __attribute__((ext_vector_type(2)));

template<int CTRL, int RM>
__device__ __forceinline__ unsigned long long dpp_umax64(unsigned long long pk) {
    unsigned lo = (unsigned)__builtin_amdgcn_update_dpp(
        0, (int)(unsigned)pk, CTRL, RM, 0xf, true);
    unsigned hi = (unsigned)__builtin_amdgcn_update_dpp(
        0, (int)(unsigned)(pk >> 32), CTRL, RM, 0xf, true);
    unsigned long long o = ((unsigned long long)hi << 32) | (unsigned long long)lo;
    return (o > pk) ? o : pk;
}

__device__ __forceinline__ unsigned long long wave_max_key(unsigned long long pk) {
    pk = dpp_umax64<0x111, 0xf>(pk);   // row_shr:1
    pk = dpp_umax64<0x112, 0xf>(pk);   // row_shr:2
    pk = dpp_umax64<0x114, 0xf>(pk);   // row_shr:4
    pk = dpp_umax64<0x118, 0xf>(pk);   // row_shr:8
    pk = dpp_umax64<0x142, 0xa>(pk);   // row_bcast15 -> rows 1,3
    pk = dpp_umax64<0x143, 0xc>(pk);   // row_bcast31 -> rows 2,3
    return pk;                          // lane 63 holds the wave max
}

__device__ __forceinline__ unsigned reduce8_widx(const unsigned long long* wk,
                                                 int lane) {
    unsigned long long k8 = wk[lane & 7];
    k8 = dpp_umax64<0x111, 0xf>(k8);
    k8 = dpp_umax64<0x112, 0xf>(k8);
    k8 = dpp_umax64<0x114, 0xf>(k8);
    unsigned lo = (unsigned)__builtin_amdgcn_readlane((int)(unsigned)k8, 7);
    return ~lo;   // uniform winner ORIG index (low word stored ~origidx)
}

__device__ __forceinline__ unsigned reduce2_widx(const unsigned long long* wk,
                                                 int lane) {
    unsigned long long k2 = wk[lane & 1];
    k2 = dpp_umax64<0x111, 0xf>(k2);
    unsigned lo = (unsigned)__builtin_amdgcn_readlane((int)(unsigned)k2, 1);
    return ~lo;
}

// ---------------- 512-thread exact kNN body (r8-proven) ----------------------
template<int N>
__device__ void knn_body512(const float* __restrict__ P,
                            float cx, float cy, float cz,
                            int* __restrict__ out, char* arena) {
    constexpr int K = KNN_;
    constexpr int CAP = 224;
    const int t = threadIdx.x;
    const int lane = t & 63;
    const int w = t >> 6;

    int*      hist = (int*)arena;                       // 8 KB
    unsigned* eqk  = (unsigned*)(arena + 8192);
    int*      eqi  = (int*)(arena + 8192 + 896);
    int*      wsum = (int*)(arena + 8192 + 1792);
    int*      ctrl = (int*)(arena + 8192 + 1824);

    unsigned prefix = 0; int pbits = 0;
    unsigned Tlo = 0; unsigned long long Thi = 0x100000000ull;
    int L = 0, target = K, Cbin = N;

    for (int round = 0; round < 3; ++round) {
        const int bits  = (round < 2) ? 11 : 10;
        const int nbins = 1 << bits;
        const int shift = 32 - pbits - bits;
        for (int i = t; i < nbins; i += 512) hist[i] = 0;
        __syncthreads();
        for (int j = t; j < N; j += 512) {
            float d = sqdist_exact(P[j * 3], P[j * 3 + 1], P[j * 3 + 2], cx, cy, cz);
            unsigned key = __float_as_uint(d);
            if (key >= Tlo && (unsigned long long)key < Thi)
                atomicAdd(&hist[(key >> shift) & (nbins - 1)], 1);
        }
        __syncthreads();
        const int per = nbins / 512;
        int s = 0;
        for (int i = 0; i < per; ++i) s += hist[t * per + i];
        int cum = s;
        for (int off = 1; off < 64; off <<= 1) {
            int o = __shfl_up(cum, off);
            if (lane >= off) cum += o;
        }
        if (lane == 63) wsum[w] = cum;
        __syncthreads();
        int wpre = 0;
        for (int i = 0; i < w; ++i) wpre += wsum[i];
        cum += wpre;
        const int cumex = cum - s;
        if ((cumex < target) && (cum >= target)) {   // exactly one thread
            int acc = cumex;
            for (int i = 0; i < per; ++i) {
                int h = hist[t * per + i];
                if (acc + h >= target) { ctrl[2] = t * per + i; ctrl[3] = acc; ctrl[4] = h; break; }
                acc += h;
            }
        }
        __syncthreads();
        const int binsel = ctrl[2];
        const int Ladd   = ctrl[3];
        const int bincnt = ctrl[4];
        L += Ladd;
        target -= Ladd;
        prefix = (prefix << bits) | (unsigned)binsel;
        pbits += bits;
        Tlo = prefix << (32 - pbits);
        Thi = ((unsigned long long)prefix + 1ull) << (32 - pbits);
        Cbin = bincnt;
        __syncthreads();
        if (Cbin <= CAP) break;
    }

    if (t == 0) { ctrl[0] = 0; ctrl[1] = 0; }
    __syncthreads();

    if (Cbin <= CAP) {
        for (int j = t; j < N; j += 512) {
            float d = sqdist_exact(P[j * 3], P[j * 3 + 1], P[j * 3 + 2], cx, cy, cz);
            unsigned key = __float_as_uint(d);
            if (key < Tlo) {
                int p = atomicAdd(&ctrl[0], 1);
                out[p] = j;
            } else if ((unsigned long long)key < Thi) {
                int p = atomicAdd(&ctrl[1], 1);
                eqk[p] = key; eqi[p] = j;
            }
        }
        __syncthreads();
        const int E = ctrl[1];
        for (int e = t; e < E; e += 512) {
            unsigned ke = eqk[e]; int ie = eqi[e];
            int rank = 0;
            for (int f = 0; f < E; ++f) {
                unsigned kf = eqk[f]; int jf = eqi[f];
                rank += (kf < ke || (kf == ke && jf < ie)) ? 1 : 0;
            }
            if (rank < target) out[L + rank] = ie;
        }
    } else {
        // giant tie class (never hit on real data): wave 0 only, no barriers
        if (t < 64) {
            int cnt = 0;
            for (int jb = 0; jb < N; jb += 64) {
                int j = jb + lane;
                float d = sqdist_exact(P[j * 3], P[j * 3 + 1], P[j * 3 + 2], cx, cy, cz);
                unsigned key = __float_as_uint(d);
                if (key < Tlo) {
                    int p = atomicAdd(&ctrl[0], 1);
                    out[p] = j;
                }
                bool eq = (key == Tlo);
                unsigned long long mb = __ballot(eq);
                int below = __popcll(mb & ((1ull << lane) - 1ull));
                if (eq && (cnt + below) < target) out[L + cnt + below] = j;
                cnt += (int)__popcll(mb);
            }
        }
    }
}

// ---------------- megakernel: AABB-pruned fps1 (0..3) + proj + knn1 ----------
// fps publishes 64-center chunks (r8-proven); knn blocks chunk-major poll
// t0-only + s_sleep, read centers via relaxed agent atomics.
// NEW (r14): points Morton-sorted; each wave owns a compact 3D region with an
// exact AABB. Skip test: if 0.999*boxdist2 >= wave's exact max dmin, the
// update is a provable no-op for every point in the region (0.999 margin
// rigorously covers fp rounding) -> wave skips phase A, republishing its
// frozen (still exact) wave-best key. Waves sharing a SIMD (w, w+4) get
// ADJACENT Morton ranges so their skips correlate (idle SIMD needs both).
// scid hoisted to pinned registers (r10 re-read it from L2 every iter).
__global__ __attribute__((amdgpu_flat_work_group_size(512, 512)))
__attribute__((amdgpu_waves_per_eu(2, 2)))
void mega1_kernel(const float* __restrict__ xyz,
                  const float* __restrict__ sx, const float* __restrict__ sy,
                  const float* __restrict__ sz, const unsigned* __restrict__ scid,
                  const float* __restrict__ Wp, const float* __restrict__ bp,
                  float* __restrict__ feats0, float* __restrict__ centers1,
                  int* __restrict__ nidx1, unsigned* __restrict__ prog) {
#pragma clang fp contract(off)
    __shared__ alignas(16) char arena[24832];
    asm volatile("" ::: "v255");           // r8-proven partitioning behavior
    const int bid = blockIdx.x;
    const int t = threadIdx.x;

    if (bid >= B_ + PROJ_BLKS_) {
        // ================= kNN path (chunk-major order) =================
        const int k = bid - (B_ + PROJ_BLKS_);
        const int c = k >> 8;              // chunk 0..31
        const int b = (k >> 6) & 3;        // batch
        const int m = c * 64 + (k & 63);   // center index
        if (t == 0) {
            while (__hip_atomic_load(&prog[b * 16], __ATOMIC_RELAXED,
                                     __HIP_MEMORY_SCOPE_AGENT) <= (unsigned)c)
                __builtin_amdgcn_s_sleep(16);
        }
        __syncthreads();
        const unsigned* cw = (const unsigned*)(centers1 + ((size_t)b * M1_ + m) * 3);
        float cx = __uint_as_float(__hip_atomic_load(cw + 0, __ATOMIC_RELAXED, __HIP_MEMORY_SCOPE_AGENT));
        float cy = __uint_as_float(__hip_atomic_load(cw + 1, __ATOMIC_RELAXED, __HIP_MEMORY_SCOPE_AGENT));
        float cz = __uint_as_float(__hip_atomic_load(cw + 2, __ATOMIC_RELAXED, __HIP_MEMORY_SCOPE_AGENT));
        knn_body512<N1_>(xyz + (size_t)b * N1_ * 3, cx, cy, cz,
                         nidx1 + ((size_t)b * M1_ + m) * KNN_, arena);
        return;
    }
    if (bid >= B_) {
        // ================= projection path =================
        int tid = (bid - B_) * 512 + t;
        int cc = tid & (PROJ_ - 1);
        int pn = tid >> 6;
        const float* p = xyz + (size_t)pn * 3;
        float acc = p[0] * Wp[0 * PROJ_ + cc];
        acc = __fmaf_rn(p[1], Wp[1 * PROJ_ + cc], acc);
        acc = __fmaf_rn(p[2], Wp[2 * PROJ_ + cc], acc);
        feats0[tid] = acc + bp[cc];
        return;
    }
    // ================= FPS stage 1 path (AABB-pruned) =======================
    constexpr int NT = 512;
    constexpr int NW = NT / 64;          // 8
    constexpr int PPT = N1_ / NT;        // 32, contiguous chunk per thread
    const int b = bid;
    const int w = t >> 6;
    const int lane = t & 63;
    const float* P  = xyz + (size_t)b * N1_ * 3;      // ORIGINAL order
    const float* SX = sx + (size_t)b * N1_;
    const float* SY = sy + (size_t)b * N1_;
    const float* SZ = sz + (size_t)b * N1_;
    const unsigned* SC = scid + (size_t)b * N1_;
    float* C1 = centers1 + (size_t)b * M1_ * 3;
    // SIMD-pairing remap: waves (w, w+4) share a SIMD -> give them ADJACENT
    // Morton ranges (slabs 2s, 2s+1) so their skip decisions correlate.
    const int slab = (w & 3) * 2 + (w >> 2);
    const int base = slab * (N1_ / NW) + lane * PPT;

    unsigned long long (*wkey)[NW] = (unsigned long long(*)[NW])arena;  // [2][8]
    float* cb1 = (float*)(arena + 128);                                 // 24 KB

    float px[PPT], py[PPT], pz[PPT], dmin[PPT];
    unsigned cid[PPT];
#pragma unroll
    for (int k = 0; k < PPT; ++k) {
        px[k] = SX[base + k];
        py[k] = SY[base + k];
        pz[k] = SZ[base + k];
        cid[k] = SC[base + k];
        dmin[k] = 1e10f;
    }
#pragma unroll
    for (int k = 0; k < PPT; ++k)
        asm volatile("" : "+v"(px[k]), "+v"(py[k]), "+v"(pz[k]),
                          "+v"(dmin[k]), "+v"(cid[k]));

    // exact wave AABB over its 2048 Morton-contiguous points
    float xlo = px[0], xhi = px[0], ylo = py[0], yhi = py[0],
          zlo = pz[0], zhi = pz[0];
#pragma unroll
    for (int k = 1; k < PPT; ++k) {
        xlo = fminf(xlo, px[k]); xhi = fmaxf(xhi, px[k]);
        ylo = fminf(ylo, py[k]); yhi = fmaxf(yhi, py[k]);
        zlo = fminf(zlo, pz[k]); zhi = fmaxf(zhi, pz[k]);
    }
    for (int off = 1; off < 64; off <<= 1) {
        xlo = fminf(xlo, __shfl_xor(xlo, off)); xhi = fmaxf(xhi, __shfl_xor(xhi, off));
        ylo = fminf(ylo, __shfl_xor(ylo, off)); yhi = fmaxf(yhi, __shfl_xor(yhi, off));
        zlo = fminf(zlo, __shfl_xor(zlo, off)); zhi = fmaxf(zhi, __shfl_xor(zhi, off));
    }

    unsigned long long mykey = ((unsigned long long)__float_as_uint(1e10f) << 32);
    float cx = P[0], cy = P[1], cz = P[2];

    for (int m = 0; m < M1_; ++m) {
        if (t == 0) {
            cb1[m * 3 + 0] = cx; cb1[m * 3 + 1] = cy; cb1[m * 3 + 2] = cz;
        }
        if ((m & 63) == 63) {
            // publish chunk c = m>>6 : LDS->global copy, drain, release flag
            __syncthreads();
            const int c = m >> 6;
            if (t < 48)
                ((float4*)C1)[c * 48 + t] = ((const float4*)cb1)[c * 48 + t];
            __syncthreads();               // vmcnt(0) drain: stores complete
            if (t == 0)
                __hip_atomic_store(&prog[b * 16], (unsigned)(c + 1),
                                   __ATOMIC_RELEASE, __HIP_MEMORY_SCOPE_AGENT);
        }
        if (m == M1_ - 1) break;
        const int par = m & 1;
        // ---- AABB skip test (wave-uniform, exact with rounding margin)
        const float UBval = __uint_as_float((unsigned)(mykey >> 32));
        const float ddx = fmaxf(fmaxf(xlo - cx, cx - xhi), 0.0f);
        const float ddy = fmaxf(fmaxf(ylo - cy, cy - yhi), 0.0f);
        const float ddz = fmaxf(fmaxf(zlo - cz, cz - zhi), 0.0f);
        const float bd2 = ddx * ddx + ddy * ddy + ddz * ddz;
        if (!(0.999f * bd2 >= UBval)) {
            // ---- A: brute update over the region; per-point key-max (exact,
            //         order-independent; cid holds ~origidx in registers)
            unsigned long long pk = 0;
#pragma unroll
            for (int k = 0; k < PPT; ++k) {
                float d  = sqdist_exact(px[k], py[k], pz[k], cx, cy, cz);
                float nd = fminf(dmin[k], d);
                dmin[k] = nd;
                unsigned long long kk =
                    ((unsigned long long)__float_as_uint(nd) << 32) | cid[k];
                pk = (kk > pk) ? kk : pk;
            }
            pk = wave_max_key(pk);
            unsigned klo = (unsigned)__builtin_amdgcn_readlane((int)(unsigned)pk, 63);
            unsigned khi = (unsigned)__builtin_amdgcn_readlane((int)(unsigned)(pk >> 32), 63);
            mykey = ((unsigned long long)khi << 32) | klo;
        }
        if (lane == 63) wkey[par][w] = mykey;
        __syncthreads();                   // the ONLY barrier per iter
        const unsigned widx = reduce8_widx(wkey[par], lane);  // ORIG index
        const float* cp = P + (size_t)widx * 3;
        cx = cp[0]; cy = cp[1]; cz = cp[2];
    }
}

// ---------------- FPS stage 2 body (128 threads; runs inside sa1_kernel) ----
__device__ __forceinline__ void fps2_body(const float* __restrict__ centers1,
                                          float* __restrict__ centers2,
                                          char* arena) {
#pragma clang fp contract(off)
    constexpr int NT = 128;
    constexpr int NW = 2;
    constexpr int NP = (M1_ / NT) / 2;   // 8 point-pairs
    const int b = blockIdx.x;
    const int t = threadIdx.x;
    const int w = t >> 6;
    const int lane = t & 63;
    const float* P = centers1 + (size_t)b * M1_ * 3;
    float* C = centers2 + (size_t)b * M2_ * 3;

    unsigned long long (*wkey)[NW] = (unsigned long long(*)[NW])arena;  // [2][2]
    float* cb2 = (float*)(arena + 64);

    v2f px2[NP], py2[NP], pz2[NP];
    float dmin[2 * NP];
#pragma unroll
    for (int p = 0; p < NP; ++p) {
        const int j0 = (2 * p) * NT + t;
        const int j1 = j0 + NT;
        px2[p] = (v2f){P[j0 * 3 + 0], P[j1 * 3 + 0]};
        py2[p] = (v2f){P[j0 * 3 + 1], P[j1 * 3 + 1]};
        pz2[p] = (v2f){P[j0 * 3 + 2], P[j1 * 3 + 2]};
        dmin[2 * p] = 1e10f; dmin[2 * p + 1] = 1e10f;
    }
#pragma unroll
    for (int p = 0; p < NP; ++p)
        asm volatile("" : "+v"(px2[p]), "+v"(py2[p]), "+v"(pz2[p]));

    float cx = P[0], cy = P[1], cz = P[2];

    for (int m = 0; m < M2_; ++m) {
        if (t == 0) {
            cb2[m * 3 + 0] = cx; cb2[m * 3 + 1] = cy; cb2[m * 3 + 2] = cz;
        }
        if (m == M2_ - 1) break;
        const int par = m & 1;
        const v2f c2x = {cx, cx}, c2y = {cy, cy}, c2z = {cz, cz};
        float bv = -1.0f; int bk = 0;
#pragma unroll
        for (int p = 0; p < NP; ++p) {
            v2f dx = px2[p] - c2x;
            v2f dy = py2[p] - c2y;
            v2f dz = pz2[p] - c2z;
            v2f d2 = (dx * dx + dy * dy) + dz * dz;
            float nd0 = fminf(dmin[2 * p],     d2.x);
            float nd1 = fminf(dmin[2 * p + 1], d2.y);
            dmin[2 * p]     = nd0;
            dmin[2 * p + 1] = nd1;
            bool g0 = nd0 > bv; bv = g0 ? nd0 : bv; bk = g0 ? 2 * p     : bk;
            bool g1 = nd1 > bv; bv = g1 ? nd1 : bv; bk = g1 ? 2 * p + 1 : bk;
        }
        unsigned gi = (unsigned)(bk * NT + t);
        unsigned long long pk =
            ((unsigned long long)__float_as_uint(bv) << 32) | (unsigned)(~gi);
        pk = wave_max_key(pk);
        if (lane == 63) wkey[par][w] = pk;
        __syncthreads();
        const unsigned widx = reduce2_widx(wkey[par], lane);
        const float* cp = P + (size_t)widx * 3;
        cx = cp[0]; cy = cp[1]; cz = cp[2];
    }
    __syncthreads();
#pragma unroll 1
    for (int i = t; i < (M2_ * 3) / 4; i += NT)
        ((float4*)C)[i] = ((const float4*)cb2)[i];
}

// ---------------- grouped 2-layer MLP + max-pool body (arena-based) ----------
template<int NPTS, int FD, int CO, int M>
__device__ __forceinline__ void mlp_body(int bm, char* arena,
                 const float* __restrict__ pts, const float* __restrict__ feats,
                 const float* __restrict__ centers, const int* __restrict__ nidx,
                 const float* __restrict__ Wa, const float* __restrict__ ba,
                 const float* __restrict__ Wb, const float* __restrict__ bb,
                 float* __restrict__ outf) {
    constexpr int KN = KNN_;
    constexpr int GS = FD + 4;
    const int b = bm / M;
    const int t = threadIdx.x;
    float (*g)[GS]  = (float(*)[GS])arena;
    float (*h1)[CO] = (float(*)[CO])(arena + sizeof(float) * KN * GS);
    const int* nb = nidx + (size_t)bm * KN;
    const float* cen = centers + (size_t)bm * 3;
    const float cx = cen[0], cy = cen[1], cz = cen[2];
    {
        constexpr int PARTS = CO / KN;
        constexpr int CHUNK = FD / PARTS;
        const int kk = t / PARTS;
        const int q  = t % PARTS;
        const int j  = nb[kk];
        const float* f = feats + ((size_t)b * NPTS + j) * FD + q * CHUNK;
        float* gr = &g[kk][q * CHUNK];
#pragma unroll
        for (int u = 0; u < CHUNK / 4; ++u)
            *(float4*)(gr + 4 * u) = *(const float4*)(f + 4 * u);
        if (q == 0) {
            const float* p = pts + ((size_t)b * NPTS + j) * 3;
            g[kk][FD + 0] = __fsub_rn(p[0], cx);
            g[kk][FD + 1] = __fsub_rn(p[1], cy);
            g[kk][FD + 2] = __fsub_rn(p[2], cz);
            g[kk][FD + 3] = 0.f;
        }
    }
    __syncthreads();
    const int o = t;
    float acc[KN];
#pragma unroll
    for (int k = 0; k < KN; ++k) acc[k] = ba[o];
    for (int s4 = 0; s4 < FD / 4; ++s4) {
        const float w0 = Wa[(4 * s4 + 3) * CO + o];
        const float w1 = Wa[(4 * s4 + 4) * CO + o];
        const float w2 = Wa[(4 * s4 + 5) * CO + o];
        const float w3 = Wa[(4 * s4 + 6) * CO + o];
#pragma unroll
        for (int k = 0; k < KN; ++k) {
            float4 gv = *(const float4*)&g[k][4 * s4];
            acc[k] = __fmaf_rn(gv.x, w0, acc[k]);
            acc[k] = __fmaf_rn(gv.y, w1, acc[k]);
            acc[k] = __fmaf_rn(gv.z, w2, acc[k]);
            acc[k] = __fmaf_rn(gv.w, w3, acc[k]);
        }
    }
    {
        const float w0 = Wa[0 * CO + o];
        const float w1 = Wa[1 * CO + o];
        const float w2 = Wa[2 * CO + o];
#pragma unroll
        for (int k = 0; k < KN; ++k) {
            float4 gv = *(const float4*)&g[k][FD];
            acc[k] = __fmaf_rn(gv.x, w0, acc[k]);
            acc[k] = __fmaf_rn(gv.y, w1, acc[k]);
            acc[k] = __fmaf_rn(gv.z, w2, acc[k]);
        }
    }
#pragma unroll
    for (int k = 0; k < KN; ++k) h1[k][o] = fmaxf(acc[k], 0.f);
    __syncthreads();
#pragma unroll
    for (int k = 0; k < KN; ++k) acc[k] = bb[o];
    for (int s4 = 0; s4 < CO / 4; ++s4) {
        const float w0 = Wb[(4 * s4 + 0) * CO + o];
        const float w1 = Wb[(4 * s4 + 1) * CO + o];
        const float w2 = Wb[(4 * s4 + 2) * CO + o];
        const float w3 = Wb[(4 * s4 + 3) * CO + o];
#pragma unroll
        for (int k = 0; k < KN; ++k) {
            float4 hv = *(const float4*)&h1[k][4 * s4];
            acc[k] = __fmaf_rn(hv.x, w0, acc[k]);
            acc[k] = __fmaf_rn(hv.y, w1, acc[k]);
            acc[k] = __fmaf_rn(hv.z, w2, acc[k]);
            acc[k] = __fmaf_rn(hv.w, w3, acc[k]);
        }
    }
    float mx = 0.f;
#pragma unroll
    for (int k = 0; k < KN; ++k) mx = fmaxf(mx, fmaxf(acc[k], 0.f));
    outf[(size_t)bm * CO + o] = mx;
}

// ---------------- kernel: mlp level-1 (blocks 4..) + FPS stage 2 (0..3) -----
__global__ void __launch_bounds__(C1_)
sa1_kernel(const float* __restrict__ xyz, const float* __restrict__ feats0,
           const float* __restrict__ centers1, const int* __restrict__ nidx1,
           const float* __restrict__ W1a, const float* __restrict__ b1a,
           const float* __restrict__ W1b, const float* __restrict__ b1b,
           float* __restrict__ feats1, float* __restrict__ centers2) {
    constexpr size_t MLP_BYTES =
        sizeof(float) * (KNN_ * (PROJ_ + 4) + KNN_ * C1_);   // 25088
    __shared__ alignas(16) char arena[MLP_BYTES];
    if (blockIdx.x < B_) {
        fps2_body(centers1, centers2, arena);
        return;
    }
    mlp_body<N1_, PROJ_, C1_, M1_>(blockIdx.x - B_, arena, xyz, feats0,
                                   centers1, nidx1, W1a, b1a, W1b, b1b, feats1);
}

// ---------------- standalone mlp kernel (level 2) ----------------
template<int NPTS, int FD, int CO, int M>
__global__ void __launch_bounds__(CO)
group_mlp_kernel(const float* __restrict__ pts, const float* __restrict__ feats,
                 const float* __restrict__ centers, const int* __restrict__ nidx,
                 const float* __restrict__ Wa, const float* __restrict__ ba,
                 const float* __restrict__ Wb, const float* __restrict__ bb,
                 float* __restrict__ outf) {
    constexpr size_t BYTES = sizeof(float) * (KNN_ * (FD + 4) + KNN_ * CO);
    __shared__ alignas(16) char arena[BYTES];
    mlp_body<NPTS, FD, CO, M>(blockIdx.x, arena, pts, feats, centers, nidx,
                              Wa, ba, Wb, bb, outf);
}

// ---------------- exact kNN, 64-thread version (knn level 2) ----------------
template<int N, int M>
__global__ void __launch_bounds__(64)
knn_kernel(const float* __restrict__ pts, const float* __restrict__ centers,
           int* __restrict__ nidx) {
    constexpr int K = KNN_;
    constexpr int CAP = 224;
    const int bm = blockIdx.x;
    const int b = bm / M;
    const int lane = threadIdx.x;
    const float* P = pts + (size_t)b * N * 3;
    const float* c = centers + (size_t)bm * 3;
    const float cx = c[0], cy = c[1], cz = c[2];
    int* out = nidx + (size_t)bm * K;

    __shared__ int hist[2048];
    __shared__ unsigned int eqk[CAP];
    __shared__ int eqi[CAP];
    __shared__ int cnt_less, cnt_eq;

    unsigned int prefix = 0; int pbits = 0;
    unsigned int Tlo = 0; unsigned long long Thi = 0x100000000ull;
    int L = 0, target = K, Cbin = N;

    for (int round = 0; round < 3; ++round) {
        const int bits  = (round < 2) ? 11 : 10;
        const int nbins = 1 << bits;
        const int shift = 32 - pbits - bits;
        for (int i = lane; i < nbins; i += 64) hist[i] = 0;
        __syncthreads();
        for (int j = lane; j < N; j += 64) {
            float d = sqdist_exact(P[j * 3], P[j * 3 + 1], P[j * 3 + 2], cx, cy, cz);
            unsigned int key = __float_as_uint(d);
            if (key >= Tlo && (unsigned long long)key < Thi)
                atomicAdd(&hist[(key >> shift) & (nbins - 1)], 1);
        }
        __syncthreads();
        const int per = nbins / 64;
        int s = 0;
        for (int i = 0; i < per; ++i) s += hist[lane * per + i];
        int cum = s;
        for (int off = 1; off < 64; off <<= 1) {
            int o = __shfl_up(cum, off);
            if (lane >= off) cum += o;
        }
        int cumex = cum - s;
        bool has = (cumex < target) && (cum >= target);
        unsigned long long ball = __ballot(has);
        int src = __ffsll(ball) - 1;
        int binsel = 0, Ladd = 0, bincnt = 0;
        if (lane == src) {
            int acc = cumex;
            for (int i = 0; i < per; ++i) {
                int h = hist[lane * per + i];
                if (acc + h >= target) { binsel = lane * per + i; Ladd = acc; bincnt = h; break; }
                acc += h;
            }
        }
        binsel = __shfl(binsel, src);
        Ladd   = __shfl(Ladd, src);
        bincnt = __shfl(bincnt, src);
        L += Ladd;
        target -= Ladd;
        prefix = (prefix << bits) | (unsigned int)binsel;
        pbits += bits;
        Tlo = prefix << (32 - pbits);
        Thi = ((unsigned long long)prefix + 1ull) << (32 - pbits);
        Cbin = bincnt;
        __syncthreads();
        if (Cbin <= CAP) break;
    }

    if (lane == 0) { cnt_less = 0; cnt_eq = 0; }
    __syncthreads();

    if (Cbin <= CAP) {
        for (int j = lane; j < N; j += 64) {
            float d = sqdist_exact(P[j * 3], P[j * 3 + 1], P[j * 3 + 2], cx, cy, cz);
            unsigned int key = __float_as_uint(d);
            if (key < Tlo) {
                int p = atomicAdd(&cnt_less, 1);
                out[p] = j;
            } else if ((unsigned long long)key < Thi) {
                int p = atomicAdd(&cnt_eq, 1);
                eqk[p] = key; eqi[p] = j;
            }
        }
        __syncthreads();
        const int E = cnt_eq;
        for (int e = lane; e < E; e += 64) {
            unsigned int ke = eqk[e]; int ie = eqi[e];
            int rank = 0;
            for (int f = 0; f < E; ++f) {
                unsigned int kf = eqk[f]; int jf = eqi[f];
                rank += (kf < ke || (kf == ke && jf < ie)) ? 1 : 0;
            }
            if (rank < target) out[L + rank] = ie;
        }
    } else {
        int cnt = 0;
        for (int jb = 0; jb < N; jb += 64) {
            int j = jb + lane;
            float d = sqdist_exact(P[j * 3], P[j * 3 + 1], P[j * 3 + 2], cx, cy, cz);
            unsigned int key = __float_as_uint(d);
            if (key < Tlo) {
                int p = atomicAdd(&cnt_less, 1);
                out[p] = j;
            }
            bool eq = (key == Tlo);
            unsigned long long mb = __ballot(eq);
            int below = __popcll(mb & ((1ull << lane) - 1ull));
            if (eq && (cnt + below) < target) out[L + cnt + below] = j;
            cnt += (int)__popcll(mb);
        }
    }
}

// ---------------- global head ----------------
__global__ void __launch_bounds__(256)
head_kernel(const float* __restrict__ feats2,
            const float* __restrict__ Wd1, const float* __restrict__ bd1,
            const float* __restrict__ Wd2, const float* __restrict__ bd2,
            float* __restrict__ outp) {
    const int b = blockIdx.x, t = threadIdx.x;
    __shared__ float gsh[2 * C2_];
    __shared__ float hsh[512];
    const float* F = feats2 + (size_t)b * M2_ * C2_;
    float mx = -1e30f, sm = 0.f;
    for (int r = 0; r < M2_; ++r) {
        float v = F[r * C2_ + t];
        mx = fmaxf(mx, v);
        sm += v;
    }
    gsh[t] = mx;
    gsh[C2_ + t] = sm * (1.0f / (float)M2_);
    __syncthreads();
#pragma unroll
    for (int oo = 0; oo < 2; ++oo) {
        const int o = t + oo * 256;
        float acc = bd1[o];
        for (int i = 0; i < 512; ++i)
            acc = __fmaf_rn(gsh[i], Wd1[i * 512 + o], acc);
        hsh[o] = fmaxf(acc, 0.f);
    }
    __syncthreads();
    float acc = bd2[t];
    for (int i = 0; i < 512; ++i)
        acc = __fmaf_rn(hsh[i], Wd2[i * 256 + t], acc);
    outp[b * 256 + t] = acc;
}

extern "C" void kernel_launch(void* const* d_in, const int* in_sizes, int n_in,
                              void* d_out, int out_size, void* d_ws, size_t ws_size,
                              hipStream_t stream) {
    const float* xyz = (const float*)d_in[0];
    const float* Wp  = (const float*)d_in[1];
    const float* bp  = (const float*)d_in[2];
    const float* W1a = (const float*)d_in[3];
    const float* b1a = (const float*)d_in[4];
    const float* W1b = (const float*)d_in[5];
    const float* b1b = (const float*)d_in[6];
    const float* W2a = (const float*)d_in[7];
    const float* b2a = (const float*)d_in[8];
    const float* W2b = (const float*)d_in[9];
    const float* b2b = (const float*)d_in[10];
    const float* Wd1 = (const float*)d_in[11];
    const float* bd1 = (const float*)d_in[12];
    const float* Wd2 = (const float*)d_in[13];
    const float* bd2 = (const float*)d_in[14];
    float* out = (float*)d_out;

    char* ws = (char*)d_ws;
    size_t off = 0;
    auto alloc = [&](size_t bytes) { void* p = ws + off; off += (bytes + 255) & ~(size_t)255; return p; };
    float* feats0   = (float*)alloc((size_t)B_ * N1_ * PROJ_ * 4);
    float* centers1 = (float*)alloc((size_t)B_ * M1_ * 3 * 4);
    int*   nidx1    = (int*)  alloc((size_t)B_ * M1_ * KNN_ * 4);
    float* feats1   = (float*)alloc((size_t)B_ * M1_ * C1_ * 4);
    float* centers2 = (float*)alloc((size_t)B_ * M2_ * 3 * 4);
    int*   nidx2    = (int*)  alloc((size_t)B_ * M2_ * KNN_ * 4);
    float* feats2   = (float*)alloc((size_t)B_ * M2_ * C2_ * 4);
    unsigned* prog  = (unsigned*)alloc(B_ * 16 * 4);   // 64B-strided flags
    float* sx       = (float*)alloc((size_t)B_ * N1_ * 4);
    float* sy       = (float*)alloc((size_t)B_ * N1_ * 4);
    float* sz       = (float*)alloc((size_t)B_ * N1_ * 4);
    unsigned* scid  = (unsigned*)alloc((size_t)B_ * N1_ * 4);
    (void)in_sizes; (void)n_in; (void)out_size; (void)ws_size;

    // zero chunk-progress flags every launch (graph replays must not see stale)
    hipMemsetAsync(prog, 0, B_ * 16 * 4, stream);

    // 0: Morton sort for AABB-pruned FPS (~40 us, 4 blocks)
    sortm_kernel<<<dim3(B_), dim3(1024), 0, stream>>>(xyz, sx, sy, sz, scid);
    // 1: AABB-pruned fps1 (blocks 0..3) + proj (8192) + chunk-pipelined knn1 (8192)
    mega1_kernel<<<dim3(B_ + PROJ_BLKS_ + KNN_BLKS_), dim3(512), 0, stream>>>(
        xyz, sx, sy, sz, scid, Wp, bp, feats0, centers1, nidx1, prog);
    // 2: MLP level 1 (blocks 4..) + FPS stage 2 (blocks 0..3)
    sa1_kernel<<<dim3(B_ + B_ * M1_), dim3(C1_), 0, stream>>>(
        xyz, feats0, centers1, nidx1, W1a, b1a, W1b, b1b, feats1, centers2);
    // 3: kNN level 2
    knn_kernel<M1_, M2_><<<dim3(B_ * M2_), dim3(64), 0, stream>>>(centers1, centers2, nidx2);
    // 4: MLP level 2
    group_mlp_kernel<M1_, C1_, C2_, M2_><<<dim3(B_ * M2_), dim3(C2_), 0, stream>>>(
        centers1, feats1, centers2, nidx2, W2a, b2a, W2b, b2b, feats2);
    // 5: head
    head_kernel<<<dim3(B_), dim3(256), 0, stream>>>(feats2, Wd1, bd1, Wd2, bd2, out);
}

// Round 12
// 3797.074 us; speedup vs baseline: 1.0826x; 1.0826x over previous
//
#include <hip/hip_runtime.h>

#define B_    4
#define N1_   16384
#define M1_   2048
#define M2_   512
#define KNN_  32
#define PROJ_ 64
#define C1_   128
#define C2_   256
#define PROJ_BLKS_ ((B_ * N1_ * PROJ_) / 512)   // 8192
#define KNN_BLKS_  ((M1_ / 64) * (B_ * 64))     // 8192 (chunk-major order)

__device__ __forceinline__ float sqdist_exact(float px, float py, float pz,
                                              float cx, float cy, float cz) {
    // Must match numpy: ((dx*dx + dy*dy) + dz*dz), no FMA contraction.
    float dx = __fsub_rn(px, cx);
    float dy = __fsub_rn(py, cy);
    float dz = __fsub_rn(pz, cz);
    return __fadd_rn(__fadd_rn(__fmul_rn(dx, dx), __fmul_rn(dy, dy)), __fmul_rn(dz, dz));
}

// relaxed agent-scope loads (LLC coherence point) for in-kernel-produced data
__device__ __forceinline__ float aload(const float* p) {
    return __uint_as_float(__hip_atomic_load((const unsigned*)p,
                           __ATOMIC_RELAXED, __HIP_MEMORY_SCOPE_AGENT));
}
__device__ __forceinline__ unsigned auload(const unsigned* p) {
    return __hip_atomic_load(p, __ATOMIC_RELAXED, __HIP_MEMORY_SCOPE_AGENT);
}

// flags layout (64B strides): prog1[b] | prog2[b] (+64) | m2done[b] (+128)
#define F_PROG1(f,b) ((f) + (b) * 16)
#define F_PROG2(f,b) ((f) + 64 + (b) * 16)
#define F_M2DONE(f,b) ((f) + 128 + (b) * 16)

// ---------------- x-sort (counting sort, 1024 bins) — r10-proven -------------
__global__ void __launch_bounds__(1024)
sortx_kernel(const float* __restrict__ xyz, float* __restrict__ sx,
             float* __restrict__ sy, float* __restrict__ sz,
             unsigned* __restrict__ scid) {
    const int b = blockIdx.x, t = threadIdx.x;
    const int lane = t & 63, w = t >> 6;
    const float* P = xyz + (size_t)b * N1_ * 3;
    __shared__ int hist[1024];
    __shared__ int wsum[16];
    hist[t] = 0;
    __syncthreads();
    for (int j = t; j < N1_; j += 1024) {
        unsigned kb = __float_as_uint(P[j * 3]);
        kb ^= (kb >> 31) ? 0xFFFFFFFFu : 0x80000000u;   // monotone float key
        atomicAdd(&hist[kb >> 22], 1);
    }
    __syncthreads();
    int v = hist[t];
    int cum = v;
    for (int off = 1; off < 64; off <<= 1) {
        int o = __shfl_up(cum, off);
        if (lane >= off) cum += o;
    }
    if (lane == 63) wsum[w] = cum;
    __syncthreads();
    int wpre = 0;
    for (int i = 0; i < w; ++i) wpre += wsum[i];
    const int excl = cum - v + wpre;
    __syncthreads();
    hist[t] = excl;
    __syncthreads();
    for (int j = t; j < N1_; j += 1024) {
        float x = P[j * 3], y = P[j * 3 + 1], z = P[j * 3 + 2];
        unsigned kb = __float_as_uint(x);
        kb ^= (kb >> 31) ? 0xFFFFFFFFu : 0x80000000u;
        int pos = atomicAdd(&hist[kb >> 22], 1);
        size_t o = (size_t)b * N1_ + pos;
        sx[o] = x; sy[o] = y; sz[o] = z; scid[o] = ~(unsigned)j;
    }
}

// ---------------- FPS primitives (proven bit-exact through r10) ---------------
// key = (f32bits(dmin) << 32) | ~origidx : u64 max == max value, tie -> min
// orig index (exactly jnp.argmax first-occurrence; order-independent).
typedef float v2f __attribute__((ext_vector_type(2)));

template<int CTRL, int RM>
__device__ __forceinline__ unsigned long long dpp_umax64(unsigned long long pk) {
    unsigned lo = (unsigned)__builtin_amdgcn_update_dpp(
        0, (int)(unsigned)pk, CTRL, RM, 0xf, true);
    unsigned hi = (unsigned)__builtin_amdgcn_update_dpp(
        0, (int)(unsigned)(pk >> 32), CTRL, RM, 0xf, true);
    unsigned long long o = ((unsigned long long)hi << 32) | (unsigned long long)lo;
    return (o > pk) ? o : pk;
}

__device__ __forceinline__ unsigned long long wave_max_key(unsigned long long pk) {
    pk = dpp_umax64<0x111, 0xf>(pk);   // row_shr:1
    pk = dpp_umax64<0x112, 0xf>(pk);   // row_shr:2
    pk = dpp_umax64<0x114, 0xf>(pk);   // row_shr:4
    pk = dpp_umax64<0x118, 0xf>(pk);   // row_shr:8
    pk = dpp_umax64<0x142, 0xa>(pk);   // row_bcast15 -> rows 1,3
    pk = dpp_umax64<0x143, 0xc>(pk);   // row_bcast31 -> rows 2,3
    return pk;                          // lane 63 holds the wave max
}

__device__ __forceinline__ unsigned reduce8_widx(const unsigned long long* wk,
                                                 int lane) {
    unsigned long long k8 = wk[lane & 7];
    k8 = dpp_umax64<0x111, 0xf>(k8);
    k8 = dpp_umax64<0x112, 0xf>(k8);
    k8 = dpp_umax64<0x114, 0xf>(k8);
    unsigned lo = (unsigned)__builtin_amdgcn_readlane((int)(unsigned)k8, 7);
    return ~lo;   // uniform winner ORIG index
}

__device__ __forceinline__ unsigned reduce2_widx(const unsigned long long* wk,
                                                 int lane) {
    unsigned long long k2 = wk[lane & 1];
    k2 = dpp_umax64<0x111, 0xf>(k2);
    unsigned lo = (unsigned)__builtin_amdgcn_readlane((int)(unsigned)k2, 1);
    return ~lo;
}

// ---------------- exact kNN body, templated width (r8-proven structure) ------
// top-32 smallest sq-dist; "less" class order arbitrary (max-pool consumer is
// permutation-invariant); eq-class cut exact, tie -> smaller index.
template<int N, int NT>
__device__ void knn_bodyT(const float* __restrict__ P,
                          float cx, float cy, float cz,
                          int* __restrict__ out, char* arena) {
    constexpr int K = KNN_;
    constexpr int CAP = 224;
    constexpr int NWV = NT / 64;
    const int t = threadIdx.x;
    const int lane = t & 63;
    const int w = t >> 6;

    int*      hist = (int*)arena;                       // 8 KB
    unsigned* eqk  = (unsigned*)(arena + 8192);
    int*      eqi  = (int*)(arena + 8192 + 896);
    int*      wsum = (int*)(arena + 8192 + 1792);
    int*      ctrl = (int*)(arena + 8192 + 1824);

    unsigned prefix = 0; int pbits = 0;
    unsigned Tlo = 0; unsigned long long Thi = 0x100000000ull;
    int L = 0, target = K, Cbin = N;

    for (int round = 0; round < 3; ++round) {
        const int bits  = (round < 2) ? 11 : 10;
        const int nbins = 1 << bits;
        const int shift = 32 - pbits - bits;
        for (int i = t; i < nbins; i += NT) hist[i] = 0;
        __syncthreads();
        for (int j = t; j < N; j += NT) {
            float d = sqdist_exact(P[j * 3], P[j * 3 + 1], P[j * 3 + 2], cx, cy, cz);
            unsigned key = __float_as_uint(d);
            if (key >= Tlo && (unsigned long long)key < Thi)
                atomicAdd(&hist[(key >> shift) & (nbins - 1)], 1);
        }
        __syncthreads();
        const int per = nbins / NT;
        int s = 0;
        for (int i = 0; i < per; ++i) s += hist[t * per + i];
        int cum = s;
        for (int off = 1; off < 64; off <<= 1) {
            int o = __shfl_up(cum, off);
            if (lane >= off) cum += o;
        }
        if (lane == 63) wsum[w] = cum;
        __syncthreads();
        int wpre = 0;
        for (int i = 0; i < w; ++i) wpre += wsum[i];
        cum += wpre;
        const int cumex = cum - s;
        if ((cumex < target) && (cum >= target)) {   // exactly one thread
            int acc = cumex;
            for (int i = 0; i < per; ++i) {
                int h = hist[t * per + i];
                if (acc + h >= target) { ctrl[2] = t * per + i; ctrl[3] = acc; ctrl[4] = h; break; }
                acc += h;
            }
        }
        __syncthreads();
        const int binsel = ctrl[2];
        const int Ladd   = ctrl[3];
        const int bincnt = ctrl[4];
        L += Ladd;
        target -= Ladd;
        prefix = (prefix << bits) | (unsigned)binsel;
        pbits += bits;
        Tlo = prefix << (32 - pbits);
        Thi = ((unsigned long long)prefix + 1ull) << (32 - pbits);
        Cbin = bincnt;
        __syncthreads();
        if (Cbin <= CAP) break;
    }

    if (t == 0) { ctrl[0] = 0; ctrl[1] = 0; }
    __syncthreads();

    if (Cbin <= CAP) {
        for (int j = t; j < N; j += NT) {
            float d = sqdist_exact(P[j * 3], P[j * 3 + 1], P[j * 3 + 2], cx, cy, cz);
            unsigned key = __float_as_uint(d);
            if (key < Tlo) {
                int p = atomicAdd(&ctrl[0], 1);
                out[p] = j;
            } else if ((unsigned long long)key < Thi) {
                int p = atomicAdd(&ctrl[1], 1);
                eqk[p] = key; eqi[p] = j;
            }
        }
        __syncthreads();
        const int E = ctrl[1];
        for (int e = t; e < E; e += NT) {
            unsigned ke = eqk[e]; int ie = eqi[e];
            int rank = 0;
            for (int f = 0; f < E; ++f) {
                unsigned kf = eqk[f]; int jf = eqi[f];
                rank += (kf < ke || (kf == ke && jf < ie)) ? 1 : 0;
            }
            if (rank < target) out[L + rank] = ie;
        }
    } else {
        // giant tie class (never hit on real data): wave 0 only, no barriers
        if (t < 64) {
            int cnt = 0;
            for (int jb = 0; jb < N; jb += 64) {
                int j = jb + lane;
                float d = sqdist_exact(P[j * 3], P[j * 3 + 1], P[j * 3 + 2], cx, cy, cz);
                unsigned key = __float_as_uint(d);
                if (key < Tlo) {
                    int p = atomicAdd(&ctrl[0], 1);
                    out[p] = j;
                }
                bool eq = (key == Tlo);
                unsigned long long mb = __ballot(eq);
                int below = __popcll(mb & ((1ull << lane) - 1ull));
                if (eq && (cnt + below) < target) out[L + cnt + below] = j;
                cnt += (int)__popcll(mb);
            }
        }
    }
}

// ---------------- megakernel: slab-pruned fps1 (0..3) + proj + knn1 ----------
// r10-proven verbatim: fps publishes 64-center chunks; knn blocks chunk-major
// poll t0-only + s_sleep, read centers via relaxed agent atomics. Skip test:
// if 0.999*dxs^2 >= wave's exact max dmin, the slab update is a provable
// no-op (0.999 margin covers fp rounding) -> wave republishes its frozen key.
__global__ __attribute__((amdgpu_flat_work_group_size(512, 512)))
__attribute__((amdgpu_waves_per_eu(2, 2)))
void mega1_kernel(const float* __restrict__ xyz,
                  const float* __restrict__ sx, const float* __restrict__ sy,
                  const float* __restrict__ sz, const unsigned* __restrict__ scid,
                  const float* __restrict__ Wp, const float* __restrict__ bp,
                  float* __restrict__ feats0, float* __restrict__ centers1,
                  int* __restrict__ nidx1, unsigned* __restrict__ prog) {
#pragma clang fp contract(off)
    __shared__ alignas(16) char arena[24832];
    asm volatile("" ::: "v255");           // r8-proven partitioning behavior
    const int bid = blockIdx.x;
    const int t = threadIdx.x;

    if (bid >= B_ + PROJ_BLKS_) {
        // ================= kNN path (chunk-major order) =================
        const int k = bid - (B_ + PROJ_BLKS_);
        const int c = k >> 8;              // chunk 0..31
        const int b = (k >> 6) & 3;        // batch
        const int m = c * 64 + (k & 63);   // center index
        if (t == 0) {
            while (auload(F_PROG1(prog, b)) <= (unsigned)c)
                __builtin_amdgcn_s_sleep(16);
        }
        __syncthreads();
        const float* cw = centers1 + ((size_t)b * M1_ + m) * 3;
        float cx = aload(cw + 0), cy = aload(cw + 1), cz = aload(cw + 2);
        knn_bodyT<N1_, 512>(xyz + (size_t)b * N1_ * 3, cx, cy, cz,
                            nidx1 + ((size_t)b * M1_ + m) * KNN_, arena);
        return;
    }
    if (bid >= B_) {
        // ================= projection path =================
        int tid = (bid - B_) * 512 + t;
        int cc = tid & (PROJ_ - 1);
        int pn = tid >> 6;
        const float* p = xyz + (size_t)pn * 3;
        float acc = p[0] * Wp[0 * PROJ_ + cc];
        acc = __fmaf_rn(p[1], Wp[1 * PROJ_ + cc], acc);
        acc = __fmaf_rn(p[2], Wp[2 * PROJ_ + cc], acc);
        feats0[tid] = acc + bp[cc];
        return;
    }
    // ================= FPS stage 1 path (x-slab-pruned, r10) ================
    constexpr int NT = 512;
    constexpr int NW = NT / 64;          // 8
    constexpr int PPT = N1_ / NT;        // 32, contiguous chunk per thread
    const int b = bid;
    const int w = t >> 6;
    const int lane = t & 63;
    const float* P  = xyz + (size_t)b * N1_ * 3;      // ORIGINAL order
    const float* SX = sx + (size_t)b * N1_;
    const float* SY = sy + (size_t)b * N1_;
    const float* SZ = sz + (size_t)b * N1_;
    const unsigned* SC = scid + (size_t)b * N1_;
    float* C1 = centers1 + (size_t)b * M1_ * 3;
    const int base = t * PPT;

    unsigned long long (*wkey)[NW] = (unsigned long long(*)[NW])arena;  // [2][8]
    float* cb1 = (float*)(arena + 128);                                 // 24 KB

    float px[PPT], py[PPT], pz[PPT], dmin[PPT];
#pragma unroll
    for (int k = 0; k < PPT; ++k) {
        px[k] = SX[base + k];
        py[k] = SY[base + k];
        pz[k] = SZ[base + k];
        dmin[k] = 1e10f;
    }
#pragma unroll
    for (int k = 0; k < PPT; ++k)
        asm volatile("" : "+v"(px[k]), "+v"(py[k]), "+v"(pz[k]), "+v"(dmin[k]));

    // exact wave slab bounds over its 2048 points
    float xlo = px[0], xhi = px[0];
#pragma unroll
    for (int k = 1; k < PPT; ++k) {
        xlo = fminf(xlo, px[k]);
        xhi = fmaxf(xhi, px[k]);
    }
    for (int off = 1; off < 64; off <<= 1) {
        xlo = fminf(xlo, __shfl_xor(xlo, off));
        xhi = fmaxf(xhi, __shfl_xor(xhi, off));
    }

    unsigned long long mykey = ((unsigned long long)__float_as_uint(1e10f) << 32);
    float cx = P[0], cy = P[1], cz = P[2];

    for (int m = 0; m < M1_; ++m) {
        if (t == 0) {
            cb1[m * 3 + 0] = cx; cb1[m * 3 + 1] = cy; cb1[m * 3 + 2] = cz;
        }
        if ((m & 63) == 63) {
            // publish chunk c = m>>6 : LDS->global copy, drain, release flag
            __syncthreads();
            const int c = m >> 6;
            if (t < 48)
                ((float4*)C1)[c * 48 + t] = ((const float4*)cb1)[c * 48 + t];
            __syncthreads();               // vmcnt(0) drain: stores complete
            if (t == 0)
                __hip_atomic_store(F_PROG1(prog, b), (unsigned)(c + 1),
                                   __ATOMIC_RELEASE, __HIP_MEMORY_SCOPE_AGENT);
        }
        if (m == M1_ - 1) break;
        const int par = m & 1;
        // ---- slab skip test (wave-uniform, exact with rounding margin)
        const float UBval = __uint_as_float((unsigned)(mykey >> 32));
        const float dxs = fmaxf(fmaxf(xlo - cx, cx - xhi), 0.0f);
        if (!(0.999f * (dxs * dxs) >= UBval)) {
            // ---- A: brute update over the slab; per-point key-max (exact)
            unsigned long long pk = 0;
#pragma unroll
            for (int k = 0; k < PPT; ++k) {
                float d  = sqdist_exact(px[k], py[k], pz[k], cx, cy, cz);
                float nd = fminf(dmin[k], d);
                dmin[k] = nd;
                unsigned long long kk =
                    ((unsigned long long)__float_as_uint(nd) << 32) | SC[base + k];
                pk = (kk > pk) ? kk : pk;
            }
            pk = wave_max_key(pk);
            unsigned klo = (unsigned)__builtin_amdgcn_readlane((int)(unsigned)pk, 63);
            unsigned khi = (unsigned)__builtin_amdgcn_readlane((int)(unsigned)(pk >> 32), 63);
            mykey = ((unsigned long long)khi << 32) | klo;
        }
        if (lane == 63) wkey[par][w] = mykey;
        __syncthreads();                   // the ONLY barrier per iter
        const unsigned widx = reduce8_widx(wkey[par], lane);  // ORIG index
        const float* cp = P + (size_t)widx * 3;
        cx = cp[0]; cy = cp[1]; cz = cp[2];
    }
}

// ---------------- FPS stage 2 body (128 threads; inside sa1), chunk publish --
__device__ __forceinline__ void fps2_body(const float* __restrict__ centers1,
                                          float* __restrict__ centers2,
                                          unsigned* __restrict__ prog,
                                          char* arena) {
#pragma clang fp contract(off)
    constexpr int NT = 128;
    constexpr int NW = 2;
    constexpr int NP = (M1_ / NT) / 2;   // 8 point-pairs
    const int b = blockIdx.x;
    const int t = threadIdx.x;
    const int w = t >> 6;
    const int lane = t & 63;
    const float* P = centers1 + (size_t)b * M1_ * 3;
    float* C = centers2 + (size_t)b * M2_ * 3;

    unsigned long long (*wkey)[NW] = (unsigned long long(*)[NW])arena;  // [2][2]
    float* cb2 = (float*)(arena + 64);

    v2f px2[NP], py2[NP], pz2[NP];
    float dmin[2 * NP];
#pragma unroll
    for (int p = 0; p < NP; ++p) {
        const int j0 = (2 * p) * NT + t;
        const int j1 = j0 + NT;
        px2[p] = (v2f){P[j0 * 3 + 0], P[j1 * 3 + 0]};
        py2[p] = (v2f){P[j0 * 3 + 1], P[j1 * 3 + 1]};
        pz2[p] = (v2f){P[j0 * 3 + 2], P[j1 * 3 + 2]};
        dmin[2 * p] = 1e10f; dmin[2 * p + 1] = 1e10f;
    }
#pragma unroll
    for (int p = 0; p < NP; ++p)
        asm volatile("" : "+v"(px2[p]), "+v"(py2[p]), "+v"(pz2[p]));

    float cx = P[0], cy = P[1], cz = P[2];

    for (int m = 0; m < M2_; ++m) {
        if (t == 0) {
            cb2[m * 3 + 0] = cx; cb2[m * 3 + 1] = cy; cb2[m * 3 + 2] = cz;
        }
        if ((m & 63) == 63) {
            // publish chunk c = m>>6 (48 float4), drain, release prog2
            __syncthreads();
            const int c = m >> 6;
            if (t < 48)
                ((float4*)C)[c * 48 + t] = ((const float4*)cb2)[c * 48 + t];
            __syncthreads();
            if (t == 0)
                __hip_atomic_store(F_PROG2(prog, b), (unsigned)(c + 1),
                                   __ATOMIC_RELEASE, __HIP_MEMORY_SCOPE_AGENT);
        }
        if (m == M2_ - 1) break;
        const int par = m & 1;
        const v2f c2x = {cx, cx}, c2y = {cy, cy}, c2z = {cz, cz};
        float bv = -1.0f; int bk = 0;
#pragma unroll
        for (int p = 0; p < NP; ++p) {
            v2f dx = px2[p] - c2x;
            v2f dy = py2[p] - c2y;
            v2f dz = pz2[p] - c2z;
            v2f d2 = (dx * dx + dy * dy) + dz * dz;
            float nd0 = fminf(dmin[2 * p],     d2.x);
            float nd1 = fminf(dmin[2 * p + 1], d2.y);
            dmin[2 * p]     = nd0;
            dmin[2 * p + 1] = nd1;
            bool g0 = nd0 > bv; bv = g0 ? nd0 : bv; bk = g0 ? 2 * p     : bk;
            bool g1 = nd1 > bv; bv = g1 ? nd1 : bv; bk = g1 ? 2 * p + 1 : bk;
        }
        unsigned gi = (unsigned)(bk * NT + t);
        unsigned long long pk =
            ((unsigned long long)__float_as_uint(bv) << 32) | (unsigned)(~gi);
        pk = wave_max_key(pk);
        if (lane == 63) wkey[par][w] = pk;
        __syncthreads();
        const unsigned widx = reduce2_widx(wkey[par], lane);
        const float* cp = P + (size_t)widx * 3;
        cx = cp[0]; cy = cp[1]; cz = cp[2];
    }
}

// ---------------- grouped 2-layer MLP + max-pool body (arena-based) ----------
template<int NPTS, int FD, int CO, int M>
__device__ __forceinline__ void mlp_body(int bm, char* arena,
                 const float* __restrict__ pts, const float* __restrict__ feats,
                 const float* __restrict__ centers, const int* __restrict__ nidx,
                 const float* __restrict__ Wa, const float* __restrict__ ba,
                 const float* __restrict__ Wb, const float* __restrict__ bb,
                 float* __restrict__ outf) {
    constexpr int KN = KNN_;
    constexpr int GS = FD + 4;
    const int b = bm / M;
    const int t = threadIdx.x;
    float (*g)[GS]  = (float(*)[GS])arena;
    float (*h1)[CO] = (float(*)[CO])(arena + sizeof(float) * KN * GS);
    const int* nb = nidx + (size_t)bm * KN;
    const float* cen = centers + (size_t)bm * 3;
    const float cx = cen[0], cy = cen[1], cz = cen[2];
    {
        constexpr int PARTS = CO / KN;
        constexpr int CHUNK = FD / PARTS;
        const int kk = t / PARTS;
        const int q  = t % PARTS;
        const int j  = nb[kk];
        const float* f = feats + ((size_t)b * NPTS + j) * FD + q * CHUNK;
        float* gr = &g[kk][q * CHUNK];
#pragma unroll
        for (int u = 0; u < CHUNK / 4; ++u)
            *(float4*)(gr + 4 * u) = *(const float4*)(f + 4 * u);
        if (q == 0) {
            const float* p = pts + ((size_t)b * NPTS + j) * 3;
            g[kk][FD + 0] = __fsub_rn(p[0], cx);
            g[kk][FD + 1] = __fsub_rn(p[1], cy);
            g[kk][FD + 2] = __fsub_rn(p[2], cz);
            g[kk][FD + 3] = 0.f;
        }
    }
    __syncthreads();
    const int o = t;
    float acc[KN];
#pragma unroll
    for (int k = 0; k < KN; ++k) acc[k] = ba[o];
    for (int s4 = 0; s4 < FD / 4; ++s4) {   // nf part: stored s -> Wa row s+3
        const float w0 = Wa[(4 * s4 + 3) * CO + o];
        const float w1 = Wa[(4 * s4 + 4) * CO + o];
        const float w2 = Wa[(4 * s4 + 5) * CO + o];
        const float w3 = Wa[(4 * s4 + 6) * CO + o];
#pragma unroll
        for (int k = 0; k < KN; ++k) {
            float4 gv = *(const float4*)&g[k][4 * s4];
            acc[k] = __fmaf_rn(gv.x, w0, acc[k]);
            acc[k] = __fmaf_rn(gv.y, w1, acc[k]);
            acc[k] = __fmaf_rn(gv.z, w2, acc[k]);
            acc[k] = __fmaf_rn(gv.w, w3, acc[k]);
        }
    }
    {
        const float w0 = Wa[0 * CO + o];
        const float w1 = Wa[1 * CO + o];
        const float w2 = Wa[2 * CO + o];
#pragma unroll
        for (int k = 0; k < KN; ++k) {
            float4 gv = *(const float4*)&g[k][FD];
            acc[k] = __fmaf_rn(gv.x, w0, acc[k]);
            acc[k] = __fmaf_rn(gv.y, w1, acc[k]);
            acc[k] = __fmaf_rn(gv.z, w2, acc[k]);
        }
    }
#pragma unroll
    for (int k = 0; k < KN; ++k) h1[k][o] = fmaxf(acc[k], 0.f);
    __syncthreads();
#pragma unroll
    for (int k = 0; k < KN; ++k) acc[k] = bb[o];
    for (int s4 = 0; s4 < CO / 4; ++s4) {
        const float w0 = Wb[(4 * s4 + 0) * CO + o];
        const float w1 = Wb[(4 * s4 + 1) * CO + o];
        const float w2 = Wb[(4 * s4 + 2) * CO + o];
        const float w3 = Wb[(4 * s4 + 3) * CO + o];
#pragma unroll
        for (int k = 0; k < KN; ++k) {
            float4 hv = *(const float4*)&h1[k][4 * s4];
            acc[k] = __fmaf_rn(hv.x, w0, acc[k]);
            acc[k] = __fmaf_rn(hv.y, w1, acc[k]);
            acc[k] = __fmaf_rn(hv.z, w2, acc[k]);
            acc[k] = __fmaf_rn(hv.w, w3, acc[k]);
        }
    }
    float mx = 0.f;
#pragma unroll
    for (int k = 0; k < KN; ++k) mx = fmaxf(mx, fmaxf(acc[k], 0.f));
    outf[(size_t)bm * CO + o] = mx;
}

// ---- sa1: fps2 (blocks 0..3, chunk-publish) | mlp1 (4..8195) | knn2 (8196..)
// knn2 polls prog2 (set by blocks 0..3, resident first -> deadlock-free),
// reads centers2 via relaxed agent atomics (in-kernel produced), centers1/xyz
// cross-kernel (plain). nidx2 consumed by the NEXT kernel (no flags needed).
__global__ void __launch_bounds__(C1_)
sa1_kernel(const float* __restrict__ xyz, const float* __restrict__ feats0,
           const float* __restrict__ centers1, const int* __restrict__ nidx1,
           const float* __restrict__ W1a, const float* __restrict__ b1a,
           const float* __restrict__ W1b, const float* __restrict__ b1b,
           float* __restrict__ feats1, float* __restrict__ centers2,
           int* __restrict__ nidx2, unsigned* __restrict__ prog) {
    constexpr size_t MLP_BYTES =
        sizeof(float) * (KNN_ * (PROJ_ + 4) + KNN_ * C1_);   // 25088
    __shared__ alignas(16) char arena[MLP_BYTES];
    const int bid = blockIdx.x;
    const int t = threadIdx.x;
    if (bid < B_) {
        fps2_body(centers1, centers2, prog, arena);
        return;
    }
    if (bid < B_ + B_ * M1_) {
        mlp_body<N1_, PROJ_, C1_, M1_>(bid - B_, arena, xyz, feats0,
                                       centers1, nidx1, W1a, b1a, W1b, b1b, feats1);
        return;
    }
    // ---- knn2 path (chunk-major over 8 chunks of 64 centers x 4 batches)
    const int k = bid - (B_ + B_ * M1_);
    const int c = k >> 8;                  // chunk 0..7
    const int b = (k >> 6) & 3;            // batch
    const int m = c * 64 + (k & 63);       // center index
    if (t == 0) {
        while (auload(F_PROG2(prog, b)) <= (unsigned)c)
            __builtin_amdgcn_s_sleep(16);
    }
    __syncthreads();
    const float* cw = centers2 + ((size_t)b * M2_ + m) * 3;
    float cx = aload(cw + 0), cy = aload(cw + 1), cz = aload(cw + 2);
    knn_bodyT<M1_, 128>(centers1 + (size_t)b * M1_ * 3, cx, cy, cz,
                        nidx2 + ((size_t)b * M2_ + m) * KNN_, arena);
}

// ---- mlp2 (blocks 0..2047) + head (blocks 2048..2051, polls m2done) --------
__global__ void __launch_bounds__(C2_)
mlp2_head_kernel(const float* __restrict__ centers1, const float* __restrict__ feats1,
                 const float* __restrict__ centers2, const int* __restrict__ nidx2,
                 const float* __restrict__ W2a, const float* __restrict__ b2a,
                 const float* __restrict__ W2b, const float* __restrict__ b2b,
                 const float* __restrict__ Wd1, const float* __restrict__ bd1,
                 const float* __restrict__ Wd2, const float* __restrict__ bd2,
                 float* __restrict__ feats2, float* __restrict__ outp,
                 unsigned* __restrict__ prog) {
    constexpr size_t BYTES = sizeof(float) * (KNN_ * (C1_ + 4) + KNN_ * C2_); // 49664
    __shared__ alignas(16) char arena[BYTES];
    const int bid = blockIdx.x;
    const int t = threadIdx.x;
    if (bid < B_ * M2_) {
        // mlp2 path: all inputs cross-kernel -> plain loads
        mlp_body<M1_, C1_, C2_, M2_>(bid, arena, centers1, feats1,
                                     centers2, nidx2, W2a, b2a, W2b, b2b, feats2);
        __syncthreads();                   // drain feats2 stores (vmcnt 0)
        if (t == 0) {
            const int b = bid / M2_;
            __hip_atomic_fetch_add(F_M2DONE(prog, b), 1u,
                                   __ATOMIC_RELEASE, __HIP_MEMORY_SCOPE_AGENT);
        }
        return;
    }
    // head path: poll this batch's mlp2 completion, read feats2 via atomics
    const int b = bid - B_ * M2_;
    if (t == 0) {
        while (auload(F_M2DONE(prog, b)) < (unsigned)M2_)
            __builtin_amdgcn_s_sleep(16);
    }
    __syncthreads();
    float* gsh = (float*)arena;                  // 2*C2 floats
    float* hsh = (float*)(arena + 2048);         // 512 floats
    const float* F = feats2 + (size_t)b * M2_ * C2_;
    float mx = -1e30f, sm = 0.f;
    for (int r = 0; r < M2_; ++r) {
        float v = aload(&F[r * C2_ + t]);
        mx = fmaxf(mx, v);
        sm += v;
    }
    gsh[t] = mx;
    gsh[C2_ + t] = sm * (1.0f / (float)M2_);
    __syncthreads();
#pragma unroll
    for (int oo = 0; oo < 2; ++oo) {
        const int o = t + oo * 256;
        float acc = bd1[o];
        for (int i = 0; i < 512; ++i)
            acc = __fmaf_rn(gsh[i], Wd1[i * 512 + o], acc);
        hsh[o] = fmaxf(acc, 0.f);
    }
    __syncthreads();
    float acc = bd2[t];
    for (int i = 0; i < 512; ++i)
        acc = __fmaf_rn(hsh[i], Wd2[i * 256 + t], acc);
    outp[b * 256 + t] = acc;
}

extern "C" void kernel_launch(void* const* d_in, const int* in_sizes, int n_in,
                              void* d_out, int out_size, void* d_ws, size_t ws_size,
                              hipStream_t stream) {
    const float* xyz = (const float*)d_in[0];
    const float* Wp  = (const float*)d_in[1];
    const float* bp  = (const float*)d_in[2];
    const float* W1a = (const float*)d_in[3];
    const float* b1a = (const float*)d_in[4];
    const float* W1b = (const float*)d_in[5];
    const float* b1b = (const float*)d_in[6];
    const float* W2a = (const float*)d_in[7];
    const float* b2a = (const float*)d_in[8];
    const float* W2b = (const float*)d_in[9];
    const float* b2b = (const float*)d_in[10];
    const float* Wd1 = (const float*)d_in[11];
    const float* bd1 = (const float*)d_in[12];
    const float* Wd2 = (const float*)d_in[13];
    const float* bd2 = (const float*)d_in[14];
    float* out = (float*)d_out;

    char* ws = (char*)d_ws;
    size_t off = 0;
    auto alloc = [&](size_t bytes) { void* p = ws + off; off += (bytes + 255) & ~(size_t)255; return p; };
    float* feats0   = (float*)alloc((size_t)B_ * N1_ * PROJ_ * 4);
    float* centers1 = (float*)alloc((size_t)B_ * M1_ * 3 * 4);
    int*   nidx1    = (int*)  alloc((size_t)B_ * M1_ * KNN_ * 4);
    float* feats1   = (float*)alloc((size_t)B_ * M1_ * C1_ * 4);
    float* centers2 = (float*)alloc((size_t)B_ * M2_ * 3 * 4);
    int*   nidx2    = (int*)  alloc((size_t)B_ * M2_ * KNN_ * 4);
    float* feats2   = (float*)alloc((size_t)B_ * M2_ * C2_ * 4);
    unsigned* prog  = (unsigned*)alloc(1024);   // prog1 | prog2 | m2done
    float* sx       = (float*)alloc((size_t)B_ * N1_ * 4);
    float* sy       = (float*)alloc((size_t)B_ * N1_ * 4);
    float* sz       = (float*)alloc((size_t)B_ * N1_ * 4);
    unsigned* scid  = (unsigned*)alloc((size_t)B_ * N1_ * 4);
    (void)in_sizes; (void)n_in; (void)out_size; (void)ws_size;

    // zero all pipeline flags each launch (graph replays must not see stale)
    hipMemsetAsync(prog, 0, 1024, stream);

    // 0: x-sort for slab-pruned FPS (~25 us, 4 blocks)
    sortx_kernel<<<dim3(B_), dim3(1024), 0, stream>>>(xyz, sx, sy, sz, scid);
    // 1: slab-pruned fps1 (0..3) + proj (8192) + chunk-pipelined knn1 (8192)
    mega1_kernel<<<dim3(B_ + PROJ_BLKS_ + KNN_BLKS_), dim3(512), 0, stream>>>(
        xyz, sx, sy, sz, scid, Wp, bp, feats0, centers1, nidx1, prog);
    // 2: fps2 (0..3) + mlp1 (8192) + chunk-pipelined knn2 (2048)
    sa1_kernel<<<dim3(B_ + B_ * M1_ + B_ * M2_), dim3(C1_), 0, stream>>>(
        xyz, feats0, centers1, nidx1, W1a, b1a, W1b, b1b, feats1,
        centers2, nidx2, prog);
    // 3: mlp2 (2048) + head (4, polls m2done)
    mlp2_head_kernel<<<dim3(B_ * M2_ + B_), dim3(C2_), 0, stream>>>(
        centers1, feats1, centers2, nidx2, W2a, b2a, W2b, b2b,
        Wd1, bd1, Wd2, bd2, feats2, out, prog);
}

// Round 13
// 3231.581 us; speedup vs baseline: 1.2721x; 1.1750x over previous
//
#include <hip/hip_runtime.h>

#define B_    4
#define N1_   16384
#define M1_   2048
#define M2_   512
#define KNN_  32
#define PROJ_ 64
#define C1_   128
#define C2_   256
#define PROJ_BLKS_ ((B_ * N1_ * PROJ_) / 512)   // 8192
#define KNN_BLKS_  ((M1_ / 64) * (B_ * 64))     // 8192 (chunk-major order)

__device__ __forceinline__ float sqdist_exact(float px, float py, float pz,
                                              float cx, float cy, float cz) {
    // Must match numpy: ((dx*dx + dy*dy) + dz*dz), no FMA contraction.
    float dx = __fsub_rn(px, cx);
    float dy = __fsub_rn(py, cy);
    float dz = __fsub_rn(pz, cz);
    return __fadd_rn(__fadd_rn(__fmul_rn(dx, dx), __fmul_rn(dy, dy)), __fmul_rn(dz, dz));
}

// relaxed agent-scope loads (LLC coherence point) for in-kernel-produced data
__device__ __forceinline__ float aload(const float* p) {
    return __uint_as_float(__hip_atomic_load((const unsigned*)p,
                           __ATOMIC_RELAXED, __HIP_MEMORY_SCOPE_AGENT));
}
__device__ __forceinline__ unsigned auload(const unsigned* p) {
    return __hip_atomic_load(p, __ATOMIC_RELAXED, __HIP_MEMORY_SCOPE_AGENT);
}

// flags layout (64B strides): prog1[b] | prog2[b] (+64) | m2done[b] (+128)
#define F_PROG1(f,b) ((f) + (b) * 16)
#define F_PROG2(f,b) ((f) + 64 + (b) * 16)
#define F_M2DONE(f,b) ((f) + 128 + (b) * 16)

// ---------------- x-sort (counting sort, 1024 bins) --------------------------
// r10-proven; round-13: also emits PACKED sorted coords sp[i]={x,y,z} so the
// FPS winner load is one contiguous 12B row indexed by SORTED index — the
// original-index array (scid) is gone from the hot loop and the workspace.
__global__ void __launch_bounds__(1024)
sortx_kernel(const float* __restrict__ xyz, float* __restrict__ sx,
             float* __restrict__ sy, float* __restrict__ sz,
             float* __restrict__ sp) {
    const int b = blockIdx.x, t = threadIdx.x;
    const int lane = t & 63, w = t >> 6;
    const float* P = xyz + (size_t)b * N1_ * 3;
    __shared__ int hist[1024];
    __shared__ int wsum[16];
    hist[t] = 0;
    __syncthreads();
    for (int j = t; j < N1_; j += 1024) {
        unsigned kb = __float_as_uint(P[j * 3]);
        kb ^= (kb >> 31) ? 0xFFFFFFFFu : 0x80000000u;   // monotone float key
        atomicAdd(&hist[kb >> 22], 1);
    }
    __syncthreads();
    int v = hist[t];
    int cum = v;
    for (int off = 1; off < 64; off <<= 1) {
        int o = __shfl_up(cum, off);
        if (lane >= off) cum += o;
    }
    if (lane == 63) wsum[w] = cum;
    __syncthreads();
    int wpre = 0;
    for (int i = 0; i < w; ++i) wpre += wsum[i];
    const int excl = cum - v + wpre;
    __syncthreads();
    hist[t] = excl;
    __syncthreads();
    for (int j = t; j < N1_; j += 1024) {
        float x = P[j * 3], y = P[j * 3 + 1], z = P[j * 3 + 2];
        unsigned kb = __float_as_uint(x);
        kb ^= (kb >> 31) ? 0xFFFFFFFFu : 0x80000000u;
        int pos = atomicAdd(&hist[kb >> 22], 1);
        size_t o = (size_t)b * N1_ + pos;
        sx[o] = x; sy[o] = y; sz[o] = z;
        float* pr = sp + ((size_t)b * N1_ + pos) * 3;
        pr[0] = x; pr[1] = y; pr[2] = z;
    }
}

// ---------------- FPS primitives (proven bit-exact through r12) ---------------
// key = (f32bits(dmin) << 32) | ~sortedidx : u64 max == max value, tie -> min
// SORTED index. (jnp.argmax ties -> min ORIGINAL index; differs only if two
// points have bit-identical dmin at a selection step — never on continuous
// random data; absmax==0.0 verifies exactly, revert if violated.)
typedef float v2f __attribute__((ext_vector_type(2)));

template<int CTRL, int RM>
__device__ __forceinline__ unsigned long long dpp_umax64(unsigned long long pk) {
    unsigned lo = (unsigned)__builtin_amdgcn_update_dpp(
        0, (int)(unsigned)pk, CTRL, RM, 0xf, true);
    unsigned hi = (unsigned)__builtin_amdgcn_update_dpp(
        0, (int)(unsigned)(pk >> 32), CTRL, RM, 0xf, true);
    unsigned long long o = ((unsigned long long)hi << 32) | (unsigned long long)lo;
    return (o > pk) ? o : pk;
}

__device__ __forceinline__ unsigned long long wave_max_key(unsigned long long pk) {
    pk = dpp_umax64<0x111, 0xf>(pk);   // row_shr:1
    pk = dpp_umax64<0x112, 0xf>(pk);   // row_shr:2
    pk = dpp_umax64<0x114, 0xf>(pk);   // row_shr:4
    pk = dpp_umax64<0x118, 0xf>(pk);   // row_shr:8
    pk = dpp_umax64<0x142, 0xa>(pk);   // row_bcast15 -> rows 1,3
    pk = dpp_umax64<0x143, 0xc>(pk);   // row_bcast31 -> rows 2,3
    return pk;                          // lane 63 holds the wave max
}

__device__ __forceinline__ unsigned reduce8_widx(const unsigned long long* wk,
                                                 int lane) {
    unsigned long long k8 = wk[lane & 7];
    k8 = dpp_umax64<0x111, 0xf>(k8);
    k8 = dpp_umax64<0x112, 0xf>(k8);
    k8 = dpp_umax64<0x114, 0xf>(k8);
    unsigned lo = (unsigned)__builtin_amdgcn_readlane((int)(unsigned)k8, 7);
    return ~lo;   // uniform winner index (space defined by key packing)
}

__device__ __forceinline__ unsigned reduce2_widx(const unsigned long long* wk,
                                                 int lane) {
    unsigned long long k2 = wk[lane & 1];
    k2 = dpp_umax64<0x111, 0xf>(k2);
    unsigned lo = (unsigned)__builtin_amdgcn_readlane((int)(unsigned)k2, 1);
    return ~lo;
}

// ---------------- exact kNN body, templated width (r8-proven structure) ------
// top-32 smallest sq-dist; "less" class order arbitrary (max-pool consumer is
// permutation-invariant); eq-class cut exact, tie -> smaller index.
template<int N, int NT>
__device__ void knn_bodyT(const float* __restrict__ P,
                          float cx, float cy, float cz,
                          int* __restrict__ out, char* arena) {
    constexpr int K = KNN_;
    constexpr int CAP = 224;
    const int t = threadIdx.x;
    const int lane = t & 63;
    const int w = t >> 6;

    int*      hist = (int*)arena;                       // 8 KB
    unsigned* eqk  = (unsigned*)(arena + 8192);
    int*      eqi  = (int*)(arena + 8192 + 896);
    int*      wsum = (int*)(arena + 8192 + 1792);
    int*      ctrl = (int*)(arena + 8192 + 1824);

    unsigned prefix = 0; int pbits = 0;
    unsigned Tlo = 0; unsigned long long Thi = 0x100000000ull;
    int L = 0, target = K, Cbin = N;

    for (int round = 0; round < 3; ++round) {
        const int bits  = (round < 2) ? 11 : 10;
        const int nbins = 1 << bits;
        const int shift = 32 - pbits - bits;
        for (int i = t; i < nbins; i += NT) hist[i] = 0;
        __syncthreads();
        for (int j = t; j < N; j += NT) {
            float d = sqdist_exact(P[j * 3], P[j * 3 + 1], P[j * 3 + 2], cx, cy, cz);
            unsigned key = __float_as_uint(d);
            if (key >= Tlo && (unsigned long long)key < Thi)
                atomicAdd(&hist[(key >> shift) & (nbins - 1)], 1);
        }
        __syncthreads();
        const int per = nbins / NT;
        int s = 0;
        for (int i = 0; i < per; ++i) s += hist[t * per + i];
        int cum = s;
        for (int off = 1; off < 64; off <<= 1) {
            int o = __shfl_up(cum, off);
            if (lane >= off) cum += o;
        }
        if (lane == 63) wsum[w] = cum;
        __syncthreads();
        int wpre = 0;
        for (int i = 0; i < w; ++i) wpre += wsum[i];
        cum += wpre;
        const int cumex = cum - s;
        if ((cumex < target) && (cum >= target)) {   // exactly one thread
            int acc = cumex;
            for (int i = 0; i < per; ++i) {
                int h = hist[t * per + i];
                if (acc + h >= target) { ctrl[2] = t * per + i; ctrl[3] = acc; ctrl[4] = h; break; }
                acc += h;
            }
        }
        __syncthreads();
        const int binsel = ctrl[2];
        const int Ladd   = ctrl[3];
        const int bincnt = ctrl[4];
        L += Ladd;
        target -= Ladd;
        prefix = (prefix << bits) | (unsigned)binsel;
        pbits += bits;
        Tlo = prefix << (32 - pbits);
        Thi = ((unsigned long long)prefix + 1ull) << (32 - pbits);
        Cbin = bincnt;
        __syncthreads();
        if (Cbin <= CAP) break;
    }

    if (t == 0) { ctrl[0] = 0; ctrl[1] = 0; }
    __syncthreads();

    if (Cbin <= CAP) {
        for (int j = t; j < N; j += NT) {
            float d = sqdist_exact(P[j * 3], P[j * 3 + 1], P[j * 3 + 2], cx, cy, cz);
            unsigned key = __float_as_uint(d);
            if (key < Tlo) {
                int p = atomicAdd(&ctrl[0], 1);
                out[p] = j;
            } else if ((unsigned long long)key < Thi) {
                int p = atomicAdd(&ctrl[1], 1);
                eqk[p] = key; eqi[p] = j;
            }
        }
        __syncthreads();
        const int E = ctrl[1];
        for (int e = t; e < E; e += NT) {
            unsigned ke = eqk[e]; int ie = eqi[e];
            int rank = 0;
            for (int f = 0; f < E; ++f) {
                unsigned kf = eqk[f]; int jf = eqi[f];
                rank += (kf < ke || (kf == ke && jf < ie)) ? 1 : 0;
            }
            if (rank < target) out[L + rank] = ie;
        }
    } else {
        // giant tie class (never hit on real data): wave 0 only, no barriers
        if (t < 64) {
            int cnt = 0;
            for (int jb = 0; jb < N; jb += 64) {
                int j = jb + lane;
                float d = sqdist_exact(P[j * 3], P[j * 3 + 1], P[j * 3 + 2], cx, cy, cz);
                unsigned key = __float_as_uint(d);
                if (key < Tlo) {
                    int p = atomicAdd(&ctrl[0], 1);
                    out[p] = j;
                }
                bool eq = (key == Tlo);
                unsigned long long mb = __ballot(eq);
                int below = __popcll(mb & ((1ull << lane) - 1ull));
                if (eq && (cnt + below) < target) out[L + cnt + below] = j;
                cnt += (int)__popcll(mb);
            }
        }
    }
}

// ---------------- megakernel: slab-pruned fps1 (0..3) + proj + knn1 ----------
// r10/r12-proven: fps publishes 64-center chunks; knn blocks chunk-major poll
// t0-only + s_sleep, read centers via relaxed agent atomics. Skip test:
// if 0.999*dxs^2 >= wave's exact max dmin, the slab update is a provable
// no-op (0.999 margin covers fp rounding) -> wave republishes its frozen key.
// r13: argmax keys carry SORTED indices computed in-register ((~base)-k) —
// the 32 per-iteration scid loads are gone; winner coords come from packed sp.
__global__ __attribute__((amdgpu_flat_work_group_size(512, 512)))
__attribute__((amdgpu_waves_per_eu(2, 2)))
void mega1_kernel(const float* __restrict__ xyz,
                  const float* __restrict__ sx, const float* __restrict__ sy,
                  const float* __restrict__ sz, const float* __restrict__ sp,
                  const float* __restrict__ Wp, const float* __restrict__ bp,
                  float* __restrict__ feats0, float* __restrict__ centers1,
                  int* __restrict__ nidx1, unsigned* __restrict__ prog) {
#pragma clang fp contract(off)
    __shared__ alignas(16) char arena[24832];
    asm volatile("" ::: "v255");           // r8-proven partitioning behavior
    const int bid = blockIdx.x;
    const int t = threadIdx.x;

    if (bid >= B_ + PROJ_BLKS_) {
        // ================= kNN path (chunk-major order) =================
        const int k = bid - (B_ + PROJ_BLKS_);
        const int c = k >> 8;              // chunk 0..31
        const int b = (k >> 6) & 3;        // batch
        const int m = c * 64 + (k & 63);   // center index
        if (t == 0) {
            while (auload(F_PROG1(prog, b)) <= (unsigned)c)
                __builtin_amdgcn_s_sleep(16);
        }
        __syncthreads();
        const float* cw = centers1 + ((size_t)b * M1_ + m) * 3;
        float cx = aload(cw + 0), cy = aload(cw + 1), cz = aload(cw + 2);
        knn_bodyT<N1_, 512>(xyz + (size_t)b * N1_ * 3, cx, cy, cz,
                            nidx1 + ((size_t)b * M1_ + m) * KNN_, arena);
        return;
    }
    if (bid >= B_) {
        // ================= projection path =================
        int tid = (bid - B_) * 512 + t;
        int cc = tid & (PROJ_ - 1);
        int pn = tid >> 6;
        const float* p = xyz + (size_t)pn * 3;
        float acc = p[0] * Wp[0 * PROJ_ + cc];
        acc = __fmaf_rn(p[1], Wp[1 * PROJ_ + cc], acc);
        acc = __fmaf_rn(p[2], Wp[2 * PROJ_ + cc], acc);
        feats0[tid] = acc + bp[cc];
        return;
    }
    // ================= FPS stage 1 path (x-slab-pruned) =====================
    constexpr int NT = 512;
    constexpr int NW = NT / 64;          // 8
    constexpr int PPT = N1_ / NT;        // 32, contiguous chunk per thread
    const int b = bid;
    const int w = t >> 6;
    const int lane = t & 63;
    const float* P  = xyz + (size_t)b * N1_ * 3;      // original order (seed)
    const float* SX = sx + (size_t)b * N1_;
    const float* SY = sy + (size_t)b * N1_;
    const float* SZ = sz + (size_t)b * N1_;
    const float* SP = sp + (size_t)b * N1_ * 3;       // packed sorted coords
    float* C1 = centers1 + (size_t)b * M1_ * 3;
    const int base = t * PPT;
    const unsigned nbase = ~(unsigned)base;           // ~(base+k) == nbase - k

    unsigned long long (*wkey)[NW] = (unsigned long long(*)[NW])arena;  // [2][8]
    float* cb1 = (float*)(arena + 128);                                 // 24 KB

    float px[PPT], py[PPT], pz[PPT], dmin[PPT];
#pragma unroll
    for (int k = 0; k < PPT; ++k) {
        px[k] = SX[base + k];
        py[k] = SY[base + k];
        pz[k] = SZ[base + k];
        dmin[k] = 1e10f;
    }
#pragma unroll
    for (int k = 0; k < PPT; ++k)
        asm volatile("" : "+v"(px[k]), "+v"(py[k]), "+v"(pz[k]), "+v"(dmin[k]));

    // exact wave slab bounds over its 2048 points
    float xlo = px[0], xhi = px[0];
#pragma unroll
    for (int k = 1; k < PPT; ++k) {
        xlo = fminf(xlo, px[k]);
        xhi = fmaxf(xhi, px[k]);
    }
    for (int off = 1; off < 64; off <<= 1) {
        xlo = fminf(xlo, __shfl_xor(xlo, off));
        xhi = fmaxf(xhi, __shfl_xor(xhi, off));
    }

    unsigned long long mykey = ((unsigned long long)__float_as_uint(1e10f) << 32);
    float cx = P[0], cy = P[1], cz = P[2];

    for (int m = 0; m < M1_; ++m) {
        if (t == 0) {
            cb1[m * 3 + 0] = cx; cb1[m * 3 + 1] = cy; cb1[m * 3 + 2] = cz;
        }
        if ((m & 63) == 63) {
            // publish chunk c = m>>6 : LDS->global copy, drain, release flag
            __syncthreads();
            const int c = m >> 6;
            if (t < 48)
                ((float4*)C1)[c * 48 + t] = ((const float4*)cb1)[c * 48 + t];
            __syncthreads();               // vmcnt(0) drain: stores complete
            if (t == 0)
                __hip_atomic_store(F_PROG1(prog, b), (unsigned)(c + 1),
                                   __ATOMIC_RELEASE, __HIP_MEMORY_SCOPE_AGENT);
        }
        if (m == M1_ - 1) break;
        const int par = m & 1;
        // ---- slab skip test (wave-uniform, exact with rounding margin)
        const float UBval = __uint_as_float((unsigned)(mykey >> 32));
        const float dxs = fmaxf(fmaxf(xlo - cx, cx - xhi), 0.0f);
        if (!(0.999f * (dxs * dxs) >= UBval)) {
            // ---- A: brute update; per-point key-max, index computed in-reg
            unsigned long long pk = 0;
#pragma unroll
            for (int k = 0; k < PPT; ++k) {
                float d  = sqdist_exact(px[k], py[k], pz[k], cx, cy, cz);
                float nd = fminf(dmin[k], d);
                dmin[k] = nd;
                unsigned long long kk =
                    ((unsigned long long)__float_as_uint(nd) << 32) |
                    (unsigned)(nbase - (unsigned)k);
                pk = (kk > pk) ? kk : pk;
            }
            pk = wave_max_key(pk);
            unsigned klo = (unsigned)__builtin_amdgcn_readlane((int)(unsigned)pk, 63);
            unsigned khi = (unsigned)__builtin_amdgcn_readlane((int)(unsigned)(pk >> 32), 63);
            mykey = ((unsigned long long)khi << 32) | klo;
        }
        if (lane == 63) wkey[par][w] = mykey;
        __syncthreads();                   // the ONLY barrier per iter
        const unsigned widx = reduce8_widx(wkey[par], lane);  // SORTED index
        const float* cp = SP + (size_t)widx * 3;   // packed 12B row, L2-hot
        cx = cp[0]; cy = cp[1]; cz = cp[2];
    }
}

// ---------------- FPS stage 2 body (128 threads; inside sa1), chunk publish --
__device__ __forceinline__ void fps2_body(const float* __restrict__ centers1,
                                          float* __restrict__ centers2,
                                          unsigned* __restrict__ prog,
                                          char* arena) {
#pragma clang fp contract(off)
    constexpr int NT = 128;
    constexpr int NW = 2;
    constexpr int NP = (M1_ / NT) / 2;   // 8 point-pairs
    const int b = blockIdx.x;
    const int t = threadIdx.x;
    const int w = t >> 6;
    const int lane = t & 63;
    const float* P = centers1 + (size_t)b * M1_ * 3;
    float* C = centers2 + (size_t)b * M2_ * 3;

    unsigned long long (*wkey)[NW] = (unsigned long long(*)[NW])arena;  // [2][2]
    float* cb2 = (float*)(arena + 64);

    v2f px2[NP], py2[NP], pz2[NP];
    float dmin[2 * NP];
#pragma unroll
    for (int p = 0; p < NP; ++p) {
        const int j0 = (2 * p) * NT + t;
        const int j1 = j0 + NT;
        px2[p] = (v2f){P[j0 * 3 + 0], P[j1 * 3 + 0]};
        py2[p] = (v2f){P[j0 * 3 + 1], P[j1 * 3 + 1]};
        pz2[p] = (v2f){P[j0 * 3 + 2], P[j1 * 3 + 2]};
        dmin[2 * p] = 1e10f; dmin[2 * p + 1] = 1e10f;
    }
#pragma unroll
    for (int p = 0; p < NP; ++p)
        asm volatile("" : "+v"(px2[p]), "+v"(py2[p]), "+v"(pz2[p]));

    float cx = P[0], cy = P[1], cz = P[2];

    for (int m = 0; m < M2_; ++m) {
        if (t == 0) {
            cb2[m * 3 + 0] = cx; cb2[m * 3 + 1] = cy; cb2[m * 3 + 2] = cz;
        }
        if ((m & 63) == 63) {
            // publish chunk c = m>>6 (48 float4), drain, release prog2
            __syncthreads();
            const int c = m >> 6;
            if (t < 48)
                ((float4*)C)[c * 48 + t] = ((const float4*)cb2)[c * 48 + t];
            __syncthreads();
            if (t == 0)
                __hip_atomic_store(F_PROG2(prog, b), (unsigned)(c + 1),
                                   __ATOMIC_RELEASE, __HIP_MEMORY_SCOPE_AGENT);
        }
        if (m == M2_ - 1) break;
        const int par = m & 1;
        const v2f c2x = {cx, cx}, c2y = {cy, cy}, c2z = {cz, cz};
        float bv = -1.0f; int bk = 0;
#pragma unroll
        for (int p = 0; p < NP; ++p) {
            v2f dx = px2[p] - c2x;
            v2f dy = py2[p] - c2y;
            v2f dz = pz2[p] - c2z;
            v2f d2 = (dx * dx + dy * dy) + dz * dz;
            float nd0 = fminf(dmin[2 * p],     d2.x);
            float nd1 = fminf(dmin[2 * p + 1], d2.y);
            dmin[2 * p]     = nd0;
            dmin[2 * p + 1] = nd1;
            bool g0 = nd0 > bv; bv = g0 ? nd0 : bv; bk = g0 ? 2 * p     : bk;
            bool g1 = nd1 > bv; bv = g1 ? nd1 : bv; bk = g1 ? 2 * p + 1 : bk;
        }
        unsigned gi = (unsigned)(bk * NT + t);
        unsigned long long pk =
            ((unsigned long long)__float_as_uint(bv) << 32) | (unsigned)(~gi);
        pk = wave_max_key(pk);
        if (lane == 63) wkey[par][w] = pk;
        __syncthreads();
        const unsigned widx = reduce2_widx(wkey[par], lane);
        const float* cp = P + (size_t)widx * 3;
        cx = cp[0]; cy = cp[1]; cz = cp[2];
    }
}

// ---------------- grouped 2-layer MLP + max-pool body (arena-based) ----------
template<int NPTS, int FD, int CO, int M>
__device__ __forceinline__ void mlp_body(int bm, char* arena,
                 const float* __restrict__ pts, const float* __restrict__ feats,
                 const float* __restrict__ centers, const int* __restrict__ nidx,
                 const float* __restrict__ Wa, const float* __restrict__ ba,
                 const float* __restrict__ Wb, const float* __restrict__ bb,
                 float* __restrict__ outf) {
    constexpr int KN = KNN_;
    constexpr int GS = FD + 4;
    const int b = bm / M;
    const int t = threadIdx.x;
    float (*g)[GS]  = (float(*)[GS])arena;
    float (*h1)[CO] = (float(*)[CO])(arena + sizeof(float) * KN * GS);
    const int* nb = nidx + (size_t)bm * KN;
    const float* cen = centers + (size_t)bm * 3;
    const float cx = cen[0], cy = cen[1], cz = cen[2];
    {
        constexpr int PARTS = CO / KN;
        constexpr int CHUNK = FD / PARTS;
        const int kk = t / PARTS;
        const int q  = t % PARTS;
        const int j  = nb[kk];
        const float* f = feats + ((size_t)b * NPTS + j) * FD + q * CHUNK;
        float* gr = &g[kk][q * CHUNK];
#pragma unroll
        for (int u = 0; u < CHUNK / 4; ++u)
            *(float4*)(gr + 4 * u) = *(const float4*)(f + 4 * u);
        if (q == 0) {
            const float* p = pts + ((size_t)b * NPTS + j) * 3;
            g[kk][FD + 0] = __fsub_rn(p[0], cx);
            g[kk][FD + 1] = __fsub_rn(p[1], cy);
            g[kk][FD + 2] = __fsub_rn(p[2], cz);
            g[kk][FD + 3] = 0.f;
        }
    }
    __syncthreads();
    const int o = t;
    float acc[KN];
#pragma unroll
    for (int k = 0; k < KN; ++k) acc[k] = ba[o];
    for (int s4 = 0; s4 < FD / 4; ++s4) {   // nf part: stored s -> Wa row s+3
        const float w0 = Wa[(4 * s4 + 3) * CO + o];
        const float w1 = Wa[(4 * s4 + 4) * CO + o];
        const float w2 = Wa[(4 * s4 + 5) * CO + o];
        const float w3 = Wa[(4 * s4 + 6) * CO + o];
#pragma unroll
        for (int k = 0; k < KN; ++k) {
            float4 gv = *(const float4*)&g[k][4 * s4];
            acc[k] = __fmaf_rn(gv.x, w0, acc[k]);
            acc[k] = __fmaf_rn(gv.y, w1, acc[k]);
            acc[k] = __fmaf_rn(gv.z, w2, acc[k]);
            acc[k] = __fmaf_rn(gv.w, w3, acc[k]);
        }
    }
    {
        const float w0 = Wa[0 * CO + o];
        const float w1 = Wa[1 * CO + o];
        const float w2 = Wa[2 * CO + o];
#pragma unroll
        for (int k = 0; k < KN; ++k) {
            float4 gv = *(const float4*)&g[k][FD];
            acc[k] = __fmaf_rn(gv.x, w0, acc[k]);
            acc[k] = __fmaf_rn(gv.y, w1, acc[k]);
            acc[k] = __fmaf_rn(gv.z, w2, acc[k]);
        }
    }
#pragma unroll
    for (int k = 0; k < KN; ++k) h1[k][o] = fmaxf(acc[k], 0.f);
    __syncthreads();
#pragma unroll
    for (int k = 0; k < KN; ++k) acc[k] = bb[o];
    for (int s4 = 0; s4 < CO / 4; ++s4) {
        const float w0 = Wb[(4 * s4 + 0) * CO + o];
        const float w1 = Wb[(4 * s4 + 1) * CO + o];
        const float w2 = Wb[(4 * s4 + 2) * CO + o];
        const float w3 = Wb[(4 * s4 + 3) * CO + o];
#pragma unroll
        for (int k = 0; k < KN; ++k) {
            float4 hv = *(const float4*)&h1[k][4 * s4];
            acc[k] = __fmaf_rn(hv.x, w0, acc[k]);
            acc[k] = __fmaf_rn(hv.y, w1, acc[k]);
            acc[k] = __fmaf_rn(hv.z, w2, acc[k]);
            acc[k] = __fmaf_rn(hv.w, w3, acc[k]);
        }
    }
    float mx = 0.f;
#pragma unroll
    for (int k = 0; k < KN; ++k) mx = fmaxf(mx, fmaxf(acc[k], 0.f));
    outf[(size_t)bm * CO + o] = mx;
}

// ---- sa1: fps2 (blocks 0..3, chunk-publish) | mlp1 (4..8195) | knn2 (8196..)
__global__ void __launch_bounds__(C1_)
sa1_kernel(const float* __restrict__ xyz, const float* __restrict__ feats0,
           const float* __restrict__ centers1, const int* __restrict__ nidx1,
           const float* __restrict__ W1a, const float* __restrict__ b1a,
           const float* __restrict__ W1b, const float* __restrict__ b1b,
           float* __restrict__ feats1, float* __restrict__ centers2,
           int* __restrict__ nidx2, unsigned* __restrict__ prog) {
    constexpr size_t MLP_BYTES =
        sizeof(float) * (KNN_ * (PROJ_ + 4) + KNN_ * C1_);   // 25088
    __shared__ alignas(16) char arena[MLP_BYTES];
    const int bid = blockIdx.x;
    const int t = threadIdx.x;
    if (bid < B_) {
        fps2_body(centers1, centers2, prog, arena);
        return;
    }
    if (bid < B_ + B_ * M1_) {
        mlp_body<N1_, PROJ_, C1_, M1_>(bid - B_, arena, xyz, feats0,
                                       centers1, nidx1, W1a, b1a, W1b, b1b, feats1);
        return;
    }
    // ---- knn2 path (chunk-major over 8 chunks of 64 centers x 4 batches)
    const int k = bid - (B_ + B_ * M1_);
    const int c = k >> 8;                  // chunk 0..7
    const int b = (k >> 6) & 3;            // batch
    const int m = c * 64 + (k & 63);       // center index
    if (t == 0) {
        while (auload(F_PROG2(prog, b)) <= (unsigned)c)
            __builtin_amdgcn_s_sleep(16);
    }
    __syncthreads();
    const float* cw = centers2 + ((size_t)b * M2_ + m) * 3;
    float cx = aload(cw + 0), cy = aload(cw + 1), cz = aload(cw + 2);
    knn_bodyT<M1_, 128>(centers1 + (size_t)b * M1_ * 3, cx, cy, cz,
                        nidx2 + ((size_t)b * M2_ + m) * KNN_, arena);
}

// ---- mlp2 (blocks 0..2047) + head (blocks 2048..2051, polls m2done) --------
__global__ void __launch_bounds__(C2_)
mlp2_head_kernel(const float* __restrict__ centers1, const float* __restrict__ feats1,
                 const float* __restrict__ centers2, const int* __restrict__ nidx2,
                 const float* __restrict__ W2a, const float* __restrict__ b2a,
                 const float* __restrict__ W2b, const float* __restrict__ b2b,
                 const float* __restrict__ Wd1, const float* __restrict__ bd1,
                 const float* __restrict__ Wd2, const float* __restrict__ bd2,
                 float* __restrict__ feats2, float* __restrict__ outp,
                 unsigned* __restrict__ prog) {
    constexpr size_t BYTES = sizeof(float) * (KNN_ * (C1_ + 4) + KNN_ * C2_); // 49664
    __shared__ alignas(16) char arena[BYTES];
    const int bid = blockIdx.x;
    const int t = threadIdx.x;
    if (bid < B_ * M2_) {
        // mlp2 path: all inputs cross-kernel -> plain loads
        mlp_body<M1_, C1_, C2_, M2_>(bid, arena, centers1, feats1,
                                     centers2, nidx2, W2a, b2a, W2b, b2b, feats2);
        __syncthreads();                   // drain feats2 stores (vmcnt 0)
        if (t == 0) {
            const int b = bid / M2_;
            __hip_atomic_fetch_add(F_M2DONE(prog, b), 1u,
                                   __ATOMIC_RELEASE, __HIP_MEMORY_SCOPE_AGENT);
        }
        return;
    }
    // head path: poll this batch's mlp2 completion, read feats2 via atomics
    const int b = bid - B_ * M2_;
    if (t == 0) {
        while (auload(F_M2DONE(prog, b)) < (unsigned)M2_)
            __builtin_amdgcn_s_sleep(16);
    }
    __syncthreads();
    float* gsh = (float*)arena;                  // 2*C2 floats
    float* hsh = (float*)(arena + 2048);         // 512 floats
    const float* F = feats2 + (size_t)b * M2_ * C2_;
    float mx = -1e30f, sm = 0.f;
    for (int r = 0; r < M2_; ++r) {
        float v = aload(&F[r * C2_ + t]);
        mx = fmaxf(mx, v);
        sm += v;
    }
    gsh[t] = mx;
    gsh[C2_ + t] = sm * (1.0f / (float)M2_);
    __syncthreads();
#pragma unroll
    for (int oo = 0; oo < 2; ++oo) {
        const int o = t + oo * 256;
        float acc = bd1[o];
        for (int i = 0; i < 512; ++i)
            acc = __fmaf_rn(gsh[i], Wd1[i * 512 + o], acc);
        hsh[o] = fmaxf(acc, 0.f);
    }
    __syncthreads();
    float acc = bd2[t];
    for (int i = 0; i < 512; ++i)
        acc = __fmaf_rn(hsh[i], Wd2[i * 256 + t], acc);
    outp[b * 256 + t] = acc;
}

extern "C" void kernel_launch(void* const* d_in, const int* in_sizes, int n_in,
                              void* d_out, int out_size, void* d_ws, size_t ws_size,
                              hipStream_t stream) {
    const float* xyz = (const float*)d_in[0];
    const float* Wp  = (const float*)d_in[1];
    const float* bp  = (const float*)d_in[2];
    const float* W1a = (const float*)d_in[3];
    const float* b1a = (const float*)d_in[4];
    const float* W1b = (const float*)d_in[5];
    const float* b1b = (const float*)d_in[6];
    const float* W2a = (const float*)d_in[7];
    const float* b2a = (const float*)d_in[8];
    const float* W2b = (const float*)d_in[9];
    const float* b2b = (const float*)d_in[10];
    const float* Wd1 = (const float*)d_in[11];
    const float* bd1 = (const float*)d_in[12];
    const float* Wd2 = (const float*)d_in[13];
    const float* bd2 = (const float*)d_in[14];
    float* out = (float*)d_out;

    char* ws = (char*)d_ws;
    size_t off = 0;
    auto alloc = [&](size_t bytes) { void* p = ws + off; off += (bytes + 255) & ~(size_t)255; return p; };
    float* feats0   = (float*)alloc((size_t)B_ * N1_ * PROJ_ * 4);
    float* centers1 = (float*)alloc((size_t)B_ * M1_ * 3 * 4);
    int*   nidx1    = (int*)  alloc((size_t)B_ * M1_ * KNN_ * 4);
    float* feats1   = (float*)alloc((size_t)B_ * M1_ * C1_ * 4);
    float* centers2 = (float*)alloc((size_t)B_ * M2_ * 3 * 4);
    int*   nidx2    = (int*)  alloc((size_t)B_ * M2_ * KNN_ * 4);
    float* feats2   = (float*)alloc((size_t)B_ * M2_ * C2_ * 4);
    unsigned* prog  = (unsigned*)alloc(1024);   // prog1 | prog2 | m2done
    float* sx       = (float*)alloc((size_t)B_ * N1_ * 4);
    float* sy       = (float*)alloc((size_t)B_ * N1_ * 4);
    float* sz       = (float*)alloc((size_t)B_ * N1_ * 4);
    float* sp       = (float*)alloc((size_t)B_ * N1_ * 3 * 4);
    (void)in_sizes; (void)n_in; (void)out_size; (void)ws_size;

    // zero all pipeline flags each launch (graph replays must not see stale)
    hipMemsetAsync(prog, 0, 1024, stream);

    // 0: x-sort for slab-pruned FPS (~25 us, 4 blocks)
    sortx_kernel<<<dim3(B_), dim3(1024), 0, stream>>>(xyz, sx, sy, sz, sp);
    // 1: slab-pruned fps1 (0..3) + proj (8192) + chunk-pipelined knn1 (8192)
    mega1_kernel<<<dim3(B_ + PROJ_BLKS_ + KNN_BLKS_), dim3(512), 0, stream>>>(
        xyz, sx, sy, sz, sp, Wp, bp, feats0, centers1, nidx1, prog);
    // 2: fps2 (0..3) + mlp1 (8192) + chunk-pipelined knn2 (2048)
    sa1_kernel<<<dim3(B_ + B_ * M1_ + B_ * M2_), dim3(C1_), 0, stream>>>(
        xyz, feats0, centers1, nidx1, W1a, b1a, W1b, b1b, feats1,
        centers2, nidx2, prog);
    // 3: mlp2 (2048) + head (4, polls m2done)
    mlp2_head_kernel<<<dim3(B_ * M2_ + B_), dim3(C2_), 0, stream>>>(
        centers1, feats1, centers2, nidx2, W2a, b2a, W2b, b2b,
        Wd1, bd1, Wd2, bd2, feats2, out, prog);
}

// Round 14
// 3151.702 us; speedup vs baseline: 1.3043x; 1.0253x over previous
//
#include <hip/hip_runtime.h>

#define B_    4
#define N1_   16384
#define M1_   2048
#define M2_   512
#define KNN_  32
#define PROJ_ 64
#define C1_   128
#define C2_   256
#define PROJ_BLKS_ ((B_ * N1_ * PROJ_) / 512)   // 8192
// mega1 tail: 32 chunks x (256 knn1 + 256 mlp1) interleaved
#define TAIL_BLKS_ (32 * 512)                   // 16384

__device__ __forceinline__ float sqdist_exact(float px, float py, float pz,
                                              float cx, float cy, float cz) {
    // Must match numpy: ((dx*dx + dy*dy) + dz*dz), no FMA contraction.
    float dx = __fsub_rn(px, cx);
    float dy = __fsub_rn(py, cy);
    float dz = __fsub_rn(pz, cz);
    return __fadd_rn(__fadd_rn(__fmul_rn(dx, dx), __fmul_rn(dy, dy)), __fmul_rn(dz, dz));
}

// relaxed agent-scope loads (LLC coherence point) for in-kernel-produced data
__device__ __forceinline__ float aload(const float* p) {
    return __uint_as_float(__hip_atomic_load((const unsigned*)p,
                           __ATOMIC_RELAXED, __HIP_MEMORY_SCOPE_AGENT));
}
__device__ __forceinline__ unsigned auload(const unsigned* p) {
    return __hip_atomic_load(p, __ATOMIC_RELAXED, __HIP_MEMORY_SCOPE_AGENT);
}
// acquire fence: one local-cache invalidate per block; subsequent PLAIN
// coalesced loads observe everything published by prior RELEASE ops (r9's
// per-element atomic gathers are gone — that was the r9 fabric bomb).
__device__ __forceinline__ void afence() {
    __builtin_amdgcn_fence(__ATOMIC_ACQUIRE, "agent");
}

// flags (64B strides): prog1[4] | prog2[4] | projdone | k1done[4][32] |
// m2done[4] | k2done[4][8]
#define F_PROG1(f,b)  ((f) + (b) * 16)
#define F_PROG2(f,b)  ((f) + 64 + (b) * 16)
#define F_PROJD(f)    ((f) + 128)
#define F_K1D(f,b,c)  ((f) + 192 + ((b) * 32 + (c)) * 16)
#define F_M2D(f,b)    ((f) + 2240 + (b) * 16)
#define F_K2D(f,b,c)  ((f) + 2304 + ((b) * 8 + (c)) * 16)

// ---------------- x-sort (counting sort, 1024 bins) — r10/r13-proven ---------
__global__ void __launch_bounds__(1024)
sortx_kernel(const float* __restrict__ xyz, float* __restrict__ sx,
             float* __restrict__ sy, float* __restrict__ sz,
             float* __restrict__ sp) {
    const int b = blockIdx.x, t = threadIdx.x;
    const int lane = t & 63, w = t >> 6;
    const float* P = xyz + (size_t)b * N1_ * 3;
    __shared__ int hist[1024];
    __shared__ int wsum[16];
    hist[t] = 0;
    __syncthreads();
    for (int j = t; j < N1_; j += 1024) {
        unsigned kb = __float_as_uint(P[j * 3]);
        kb ^= (kb >> 31) ? 0xFFFFFFFFu : 0x80000000u;   // monotone float key
        atomicAdd(&hist[kb >> 22], 1);
    }
    __syncthreads();
    int v = hist[t];
    int cum = v;
    for (int off = 1; off < 64; off <<= 1) {
        int o = __shfl_up(cum, off);
        if (lane >= off) cum += o;
    }
    if (lane == 63) wsum[w] = cum;
    __syncthreads();
    int wpre = 0;
    for (int i = 0; i < w; ++i) wpre += wsum[i];
    const int excl = cum - v + wpre;
    __syncthreads();
    hist[t] = excl;
    __syncthreads();
    for (int j = t; j < N1_; j += 1024) {
        float x = P[j * 3], y = P[j * 3 + 1], z = P[j * 3 + 2];
        unsigned kb = __float_as_uint(x);
        kb ^= (kb >> 31) ? 0xFFFFFFFFu : 0x80000000u;
        int pos = atomicAdd(&hist[kb >> 22], 1);
        size_t o = (size_t)b * N1_ + pos;
        sx[o] = x; sy[o] = y; sz[o] = z;
        float* pr = sp + ((size_t)b * N1_ + pos) * 3;
        pr[0] = x; pr[1] = y; pr[2] = z;
    }
}

// ---------------- FPS primitives (proven bit-exact through r13) ---------------
typedef float v2f __attribute__((ext_vector_type(2)));

template<int CTRL, int RM>
__device__ __forceinline__ unsigned long long dpp_umax64(unsigned long long pk) {
    unsigned lo = (unsigned)__builtin_amdgcn_update_dpp(
        0, (int)(unsigned)pk, CTRL, RM, 0xf, true);
    unsigned hi = (unsigned)__builtin_amdgcn_update_dpp(
        0, (int)(unsigned)(pk >> 32), CTRL, RM, 0xf, true);
    unsigned long long o = ((unsigned long long)hi << 32) | (unsigned long long)lo;
    return (o > pk) ? o : pk;
}

__device__ __forceinline__ unsigned long long wave_max_key(unsigned long long pk) {
    pk = dpp_umax64<0x111, 0xf>(pk);   // row_shr:1
    pk = dpp_umax64<0x112, 0xf>(pk);   // row_shr:2
    pk = dpp_umax64<0x114, 0xf>(pk);   // row_shr:4
    pk = dpp_umax64<0x118, 0xf>(pk);   // row_shr:8
    pk = dpp_umax64<0x142, 0xa>(pk);   // row_bcast15 -> rows 1,3
    pk = dpp_umax64<0x143, 0xc>(pk);   // row_bcast31 -> rows 2,3
    return pk;                          // lane 63 holds the wave max
}

__device__ __forceinline__ unsigned reduce8_widx(const unsigned long long* wk,
                                                 int lane) {
    unsigned long long k8 = wk[lane & 7];
    k8 = dpp_umax64<0x111, 0xf>(k8);
    k8 = dpp_umax64<0x112, 0xf>(k8);
    k8 = dpp_umax64<0x114, 0xf>(k8);
    unsigned lo = (unsigned)__builtin_amdgcn_readlane((int)(unsigned)k8, 7);
    return ~lo;
}

__device__ __forceinline__ unsigned reduce4_widx(const unsigned long long* wk,
                                                 int lane) {
    unsigned long long k4 = wk[lane & 3];
    k4 = dpp_umax64<0x111, 0xf>(k4);
    k4 = dpp_umax64<0x112, 0xf>(k4);
    unsigned lo = (unsigned)__builtin_amdgcn_readlane((int)(unsigned)k4, 3);
    return ~lo;
}

// ---------------- exact kNN body, templated width (r8/r12-proven) ------------
template<int N, int NT>
__device__ void knn_bodyT(const float* __restrict__ P,
                          float cx, float cy, float cz,
                          int* __restrict__ out, char* arena) {
    constexpr int K = KNN_;
    constexpr int CAP = 224;
    const int t = threadIdx.x;
    const int lane = t & 63;
    const int w = t >> 6;

    int*      hist = (int*)arena;                       // 8 KB
    unsigned* eqk  = (unsigned*)(arena + 8192);
    int*      eqi  = (int*)(arena + 8192 + 896);
    int*      wsum = (int*)(arena + 8192 + 1792);
    int*      ctrl = (int*)(arena + 8192 + 1824);

    unsigned prefix = 0; int pbits = 0;
    unsigned Tlo = 0; unsigned long long Thi = 0x100000000ull;
    int L = 0, target = K, Cbin = N;

    for (int round = 0; round < 3; ++round) {
        const int bits  = (round < 2) ? 11 : 10;
        const int nbins = 1 << bits;
        const int shift = 32 - pbits - bits;
        for (int i = t; i < nbins; i += NT) hist[i] = 0;
        __syncthreads();
        for (int j = t; j < N; j += NT) {
            float d = sqdist_exact(P[j * 3], P[j * 3 + 1], P[j * 3 + 2], cx, cy, cz);
            unsigned key = __float_as_uint(d);
            if (key >= Tlo && (unsigned long long)key < Thi)
                atomicAdd(&hist[(key >> shift) & (nbins - 1)], 1);
        }
        __syncthreads();
        const int per = nbins / NT;
        int s = 0;
        for (int i = 0; i < per; ++i) s += hist[t * per + i];
        int cum = s;
        for (int off = 1; off < 64; off <<= 1) {
            int o = __shfl_up(cum, off);
            if (lane >= off) cum += o;
        }
        if (lane == 63) wsum[w] = cum;
        __syncthreads();
        int wpre = 0;
        for (int i = 0; i < w; ++i) wpre += wsum[i];
        cum += wpre;
        const int cumex = cum - s;
        if ((cumex < target) && (cum >= target)) {   // exactly one thread
            int acc = cumex;
            for (int i = 0; i < per; ++i) {
                int h = hist[t * per + i];
                if (acc + h >= target) { ctrl[2] = t * per + i; ctrl[3] = acc; ctrl[4] = h; break; }
                acc += h;
            }
        }
        __syncthreads();
        const int binsel = ctrl[2];
        const int Ladd   = ctrl[3];
        const int bincnt = ctrl[4];
        L += Ladd;
        target -= Ladd;
        prefix = (prefix << bits) | (unsigned)binsel;
        pbits += bits;
        Tlo = prefix << (32 - pbits);
        Thi = ((unsigned long long)prefix + 1ull) << (32 - pbits);
        Cbin = bincnt;
        __syncthreads();
        if (Cbin <= CAP) break;
    }

    if (t == 0) { ctrl[0] = 0; ctrl[1] = 0; }
    __syncthreads();

    if (Cbin <= CAP) {
        for (int j = t; j < N; j += NT) {
            float d = sqdist_exact(P[j * 3], P[j * 3 + 1], P[j * 3 + 2], cx, cy, cz);
            unsigned key = __float_as_uint(d);
            if (key < Tlo) {
                int p = atomicAdd(&ctrl[0], 1);
                out[p] = j;
            } else if ((unsigned long long)key < Thi) {
                int p = atomicAdd(&ctrl[1], 1);
                eqk[p] = key; eqi[p] = j;
            }
        }
        __syncthreads();
        const int E = ctrl[1];
        for (int e = t; e < E; e += NT) {
            unsigned ke = eqk[e]; int ie = eqi[e];
            int rank = 0;
            for (int f = 0; f < E; ++f) {
                unsigned kf = eqk[f]; int jf = eqi[f];
                rank += (kf < ke || (kf == ke && jf < ie)) ? 1 : 0;
            }
            if (rank < target) out[L + rank] = ie;
        }
    } else {
        // giant tie class (never hit on real data): wave 0 only, no barriers
        if (t < 64) {
            int cnt = 0;
            for (int jb = 0; jb < N; jb += 64) {
                int j = jb + lane;
                float d = sqdist_exact(P[j * 3], P[j * 3 + 1], P[j * 3 + 2], cx, cy, cz);
                unsigned key = __float_as_uint(d);
                if (key < Tlo) {
                    int p = atomicAdd(&ctrl[0], 1);
                    out[p] = j;
                }
                bool eq = (key == Tlo);
                unsigned long long mb = __ballot(eq);
                int below = __popcll(mb & ((1ull << lane) - 1ull));
                if (eq && (cnt + below) < target) out[L + cnt + below] = j;
                cnt += (int)__popcll(mb);
            }
        }
    }
}

// ---------------- mlp1 body, 512 threads (4 groups x 8 neighbors) ------------
// Per-(k,o) FMA chains VERBATIM from r13's mlp_body (bit-exact); max-pool
// reassociated via group partial-max (exact: max is order-independent).
__device__ void mlp1_512(int b, int m, char* arena,
                         const float* __restrict__ xyz,
                         const float* __restrict__ feats0,
                         const float* __restrict__ centers1,
                         const int* __restrict__ nidx1,
                         const float* __restrict__ Wa, const float* __restrict__ ba,
                         const float* __restrict__ Wb, const float* __restrict__ bb,
                         float* __restrict__ feats1) {
    constexpr int KN = KNN_, FD = PROJ_, CO = C1_, GS = FD + 4;
    const int t = threadIdx.x;
    const size_t bm = (size_t)b * M1_ + m;
    float (*g)[GS]  = (float(*)[GS])arena;                   // 8704 B
    float (*h1)[CO] = (float(*)[CO])(arena + 8704);          // 16384 B
    float (*pm)[CO] = (float(*)[CO])(arena + 8704 + 16384);  // 2048 B
    const int* nb = nidx1 + bm * KN;
    const float* cen = centers1 + bm * 3;
    const float cx = cen[0], cy = cen[1], cz = cen[2];
    {
        const int kk = t >> 4;        // 0..31
        const int q  = t & 15;        // CHUNK = 4 floats
        const int j  = nb[kk];
        const float* f = feats0 + ((size_t)b * N1_ + j) * FD + q * 4;
        *(float4*)&g[kk][q * 4] = *(const float4*)f;
        if (q == 0) {
            const float* p = xyz + ((size_t)b * N1_ + j) * 3;
            g[kk][FD + 0] = __fsub_rn(p[0], cx);
            g[kk][FD + 1] = __fsub_rn(p[1], cy);
            g[kk][FD + 2] = __fsub_rn(p[2], cz);
            g[kk][FD + 3] = 0.f;
        }
    }
    __syncthreads();
    const int o = t & (CO - 1);
    const int grp = t >> 7;           // 0..3
    const int k0 = grp * 8;
    float acc[8];
#pragma unroll
    for (int k = 0; k < 8; ++k) acc[k] = ba[o];
    for (int s4 = 0; s4 < FD / 4; ++s4) {   // nf part: stored s -> Wa row s+3
        const float w0 = Wa[(4 * s4 + 3) * CO + o];
        const float w1 = Wa[(4 * s4 + 4) * CO + o];
        const float w2 = Wa[(4 * s4 + 5) * CO + o];
        const float w3 = Wa[(4 * s4 + 6) * CO + o];
#pragma unroll
        for (int k = 0; k < 8; ++k) {
            float4 gv = *(const float4*)&g[k0 + k][4 * s4];
            acc[k] = __fmaf_rn(gv.x, w0, acc[k]);
            acc[k] = __fmaf_rn(gv.y, w1, acc[k]);
            acc[k] = __fmaf_rn(gv.z, w2, acc[k]);
            acc[k] = __fmaf_rn(gv.w, w3, acc[k]);
        }
    }
    {
        const float w0 = Wa[0 * CO + o];
        const float w1 = Wa[1 * CO + o];
        const float w2 = Wa[2 * CO + o];
#pragma unroll
        for (int k = 0; k < 8; ++k) {
            float4 gv = *(const float4*)&g[k0 + k][FD];
            acc[k] = __fmaf_rn(gv.x, w0, acc[k]);
            acc[k] = __fmaf_rn(gv.y, w1, acc[k]);
            acc[k] = __fmaf_rn(gv.z, w2, acc[k]);
        }
    }
#pragma unroll
    for (int k = 0; k < 8; ++k) h1[k0 + k][o] = fmaxf(acc[k], 0.f);
    __syncthreads();
#pragma unroll
    for (int k = 0; k < 8; ++k) acc[k] = bb[o];
    for (int s4 = 0; s4 < CO / 4; ++s4) {
        const float w0 = Wb[(4 * s4 + 0) * CO + o];
        const float w1 = Wb[(4 * s4 + 1) * CO + o];
        const float w2 = Wb[(4 * s4 + 2) * CO + o];
        const float w3 = Wb[(4 * s4 + 3) * CO + o];
#pragma unroll
        for (int k = 0; k < 8; ++k) {
            float4 hv = *(const float4*)&h1[k0 + k][4 * s4];
            acc[k] = __fmaf_rn(hv.x, w0, acc[k]);
            acc[k] = __fmaf_rn(hv.y, w1, acc[k]);
            acc[k] = __fmaf_rn(hv.z, w2, acc[k]);
            acc[k] = __fmaf_rn(hv.w, w3, acc[k]);
        }
    }
    float mx = 0.f;
#pragma unroll
    for (int k = 0; k < 8; ++k) mx = fmaxf(mx, fmaxf(acc[k], 0.f));
    pm[grp][o] = mx;
    __syncthreads();
    if (t < CO) {
        float m0 = fmaxf(fmaxf(pm[0][o], pm[1][o]), fmaxf(pm[2][o], pm[3][o]));
        feats1[bm * CO + o] = m0;
    }
}

// ---------------- mega1: fps1 | proj | 32x(knn1-chunk | mlp1-chunk) ----------
// Interleaved chunk segments give the sliding residency window real overlap
// (r9's flat ordering never reached consumers until producers drained).
__global__ __attribute__((amdgpu_flat_work_group_size(512, 512)))
__attribute__((amdgpu_waves_per_eu(2, 2)))
void mega1_kernel(const float* __restrict__ xyz,
                  const float* __restrict__ sx, const float* __restrict__ sy,
                  const float* __restrict__ sz, const float* __restrict__ sp,
                  const float* __restrict__ Wp, const float* __restrict__ bp,
                  const float* __restrict__ W1a, const float* __restrict__ b1a,
                  const float* __restrict__ W1b, const float* __restrict__ b1b,
                  float* __restrict__ feats0, float* __restrict__ centers1,
                  int* __restrict__ nidx1, float* __restrict__ feats1,
                  unsigned* __restrict__ flags) {
#pragma clang fp contract(off)
    __shared__ alignas(16) char arena[27136];
    asm volatile("" ::: "v255");           // r8-proven partitioning behavior
    const int bid = blockIdx.x;
    const int t = threadIdx.x;

    if (bid >= B_ + PROJ_BLKS_) {
        const int k = bid - (B_ + PROJ_BLKS_);
        const int c = k >> 9;              // chunk 0..31
        const int r = k & 511;
        const int i = r & 255;
        const int b = (i >> 6) & 3;
        const int m = c * 64 + (i & 63);
        if (r < 256) {
            // ============== knn1 path (waits on fps chunk publish) ==========
            if (t == 0) {
                while (auload(F_PROG1(flags, b)) <= (unsigned)c)
                    __builtin_amdgcn_s_sleep(16);
            }
            __syncthreads();
            const float* cw = centers1 + ((size_t)b * M1_ + m) * 3;
            float cx = aload(cw + 0), cy = aload(cw + 1), cz = aload(cw + 2);
            knn_bodyT<N1_, 512>(xyz + (size_t)b * N1_ * 3, cx, cy, cz,
                                nidx1 + ((size_t)b * M1_ + m) * KNN_, arena);
            __syncthreads();               // drain nidx stores (vmcnt 0)
            if (t == 0)
                __hip_atomic_fetch_add(F_K1D(flags, b, c), 1u,
                                       __ATOMIC_RELEASE, __HIP_MEMORY_SCOPE_AGENT);
            return;
        }
        // ============== mlp1 path (waits knn1 chunk + proj) =================
        if (t == 0) {
            while (auload(F_K1D(flags, b, c)) < 64u ||
                   auload(F_PROJD(flags)) < (unsigned)PROJ_BLKS_)
                __builtin_amdgcn_s_sleep(16);
        }
        __syncthreads();
        afence();                          // plain coalesced loads are now safe
        mlp1_512(b, m, arena, xyz, feats0, centers1, nidx1,
                 W1a, b1a, W1b, b1b, feats1);
        return;
    }
    if (bid >= B_) {
        // ================= projection path =================
        int tid = (bid - B_) * 512 + t;
        int cc = tid & (PROJ_ - 1);
        int pn = tid >> 6;
        const float* p = xyz + (size_t)pn * 3;
        float acc = p[0] * Wp[0 * PROJ_ + cc];
        acc = __fmaf_rn(p[1], Wp[1 * PROJ_ + cc], acc);
        acc = __fmaf_rn(p[2], Wp[2 * PROJ_ + cc], acc);
        feats0[tid] = acc + bp[cc];
        __syncthreads();                   // drain stores (vmcnt 0)
        if (t == 0)
            __hip_atomic_fetch_add(F_PROJD(flags), 1u,
                                   __ATOMIC_RELEASE, __HIP_MEMORY_SCOPE_AGENT);
        return;
    }
    // ================= FPS stage 1 path (x-slab-pruned, r13-verbatim) =======
    constexpr int NT = 512;
    constexpr int NW = NT / 64;          // 8
    constexpr int PPT = N1_ / NT;        // 32
    const int b = bid;
    const int w = t >> 6;
    const int lane = t & 63;
    const float* P  = xyz + (size_t)b * N1_ * 3;      // original order (seed)
    const float* SX = sx + (size_t)b * N1_;
    const float* SY = sy + (size_t)b * N1_;
    const float* SZ = sz + (size_t)b * N1_;
    const float* SP = sp + (size_t)b * N1_ * 3;       // packed sorted coords
    float* C1 = centers1 + (size_t)b * M1_ * 3;
    const int base = t * PPT;
    const unsigned nbase = ~(unsigned)base;           // ~(base+k) == nbase - k

    unsigned long long (*wkey)[NW] = (unsigned long long(*)[NW])arena;  // [2][8]
    float* cb1 = (float*)(arena + 128);                                 // 24 KB

    float px[PPT], py[PPT], pz[PPT], dmin[PPT];
#pragma unroll
    for (int k = 0; k < PPT; ++k) {
        px[k] = SX[base + k];
        py[k] = SY[base + k];
        pz[k] = SZ[base + k];
        dmin[k] = 1e10f;
    }
#pragma unroll
    for (int k = 0; k < PPT; ++k)
        asm volatile("" : "+v"(px[k]), "+v"(py[k]), "+v"(pz[k]), "+v"(dmin[k]));

    float xlo = px[0], xhi = px[0];
#pragma unroll
    for (int k = 1; k < PPT; ++k) {
        xlo = fminf(xlo, px[k]);
        xhi = fmaxf(xhi, px[k]);
    }
    for (int off = 1; off < 64; off <<= 1) {
        xlo = fminf(xlo, __shfl_xor(xlo, off));
        xhi = fmaxf(xhi, __shfl_xor(xhi, off));
    }

    unsigned long long mykey = ((unsigned long long)__float_as_uint(1e10f) << 32);
    float cx = P[0], cy = P[1], cz = P[2];

    for (int m = 0; m < M1_; ++m) {
        if (t == 0) {
            cb1[m * 3 + 0] = cx; cb1[m * 3 + 1] = cy; cb1[m * 3 + 2] = cz;
        }
        if ((m & 63) == 63) {
            __syncthreads();
            const int c = m >> 6;
            if (t < 48)
                ((float4*)C1)[c * 48 + t] = ((const float4*)cb1)[c * 48 + t];
            __syncthreads();               // vmcnt(0) drain: stores complete
            if (t == 0)
                __hip_atomic_store(F_PROG1(flags, b), (unsigned)(c + 1),
                                   __ATOMIC_RELEASE, __HIP_MEMORY_SCOPE_AGENT);
        }
        if (m == M1_ - 1) break;
        const int par = m & 1;
        const float UBval = __uint_as_float((unsigned)(mykey >> 32));
        const float dxs = fmaxf(fmaxf(xlo - cx, cx - xhi), 0.0f);
        if (!(0.999f * (dxs * dxs) >= UBval)) {
            unsigned long long pk = 0;
#pragma unroll
            for (int k = 0; k < PPT; ++k) {
                float d  = sqdist_exact(px[k], py[k], pz[k], cx, cy, cz);
                float nd = fminf(dmin[k], d);
                dmin[k] = nd;
                unsigned long long kk =
                    ((unsigned long long)__float_as_uint(nd) << 32) |
                    (unsigned)(nbase - (unsigned)k);
                pk = (kk > pk) ? kk : pk;
            }
            pk = wave_max_key(pk);
            unsigned klo = (unsigned)__builtin_amdgcn_readlane((int)(unsigned)pk, 63);
            unsigned khi = (unsigned)__builtin_amdgcn_readlane((int)(unsigned)(pk >> 32), 63);
            mykey = ((unsigned long long)khi << 32) | klo;
        }
        if (lane == 63) wkey[par][w] = mykey;
        __syncthreads();                   // the ONLY barrier per iter
        const unsigned widx = reduce8_widx(wkey[par], lane);  // SORTED index
        const float* cp = SP + (size_t)widx * 3;
        cx = cp[0]; cy = cp[1]; cz = cp[2];
    }
}

// ---------------- FPS stage 2 body (256 threads; inside sa2), chunk publish --
__device__ __forceinline__ void fps2_body(const float* __restrict__ centers1,
                                          float* __restrict__ centers2,
                                          unsigned* __restrict__ flags,
                                          char* arena) {
#pragma clang fp contract(off)
    constexpr int NT = 256;
    constexpr int NW = 4;
    constexpr int NP = (M1_ / NT) / 2;   // 4 point-pairs
    const int b = blockIdx.x;
    const int t = threadIdx.x;
    const int w = t >> 6;
    const int lane = t & 63;
    const float* P = centers1 + (size_t)b * M1_ * 3;
    float* C = centers2 + (size_t)b * M2_ * 3;

    unsigned long long (*wkey)[NW] = (unsigned long long(*)[NW])arena;  // [2][4]
    float* cb2 = (float*)(arena + 64);

    v2f px2[NP], py2[NP], pz2[NP];
    float dmin[2 * NP];
#pragma unroll
    for (int p = 0; p < NP; ++p) {
        const int j0 = (2 * p) * NT + t;
        const int j1 = j0 + NT;
        px2[p] = (v2f){P[j0 * 3 + 0], P[j1 * 3 + 0]};
        py2[p] = (v2f){P[j0 * 3 + 1], P[j1 * 3 + 1]};
        pz2[p] = (v2f){P[j0 * 3 + 2], P[j1 * 3 + 2]};
        dmin[2 * p] = 1e10f; dmin[2 * p + 1] = 1e10f;
    }
#pragma unroll
    for (int p = 0; p < NP; ++p)
        asm volatile("" : "+v"(px2[p]), "+v"(py2[p]), "+v"(pz2[p]));

    float cx = P[0], cy = P[1], cz = P[2];

    for (int m = 0; m < M2_; ++m) {
        if (t == 0) {
            cb2[m * 3 + 0] = cx; cb2[m * 3 + 1] = cy; cb2[m * 3 + 2] = cz;
        }
        if ((m & 63) == 63) {
            __syncthreads();
            const int c = m >> 6;
            if (t < 48)
                ((float4*)C)[c * 48 + t] = ((const float4*)cb2)[c * 48 + t];
            __syncthreads();
            if (t == 0)
                __hip_atomic_store(F_PROG2(flags, b), (unsigned)(c + 1),
                                   __ATOMIC_RELEASE, __HIP_MEMORY_SCOPE_AGENT);
        }
        if (m == M2_ - 1) break;
        const int par = m & 1;
        const v2f c2x = {cx, cx}, c2y = {cy, cy}, c2z = {cz, cz};
        float bv = -1.0f; int bk = 0;
#pragma unroll
        for (int p = 0; p < NP; ++p) {
            v2f dx = px2[p] - c2x;
            v2f dy = py2[p] - c2y;
            v2f dz = pz2[p] - c2z;
            v2f d2 = (dx * dx + dy * dy) + dz * dz;
            float nd0 = fminf(dmin[2 * p],     d2.x);
            float nd1 = fminf(dmin[2 * p + 1], d2.y);
            dmin[2 * p]     = nd0;
            dmin[2 * p + 1] = nd1;
            bool g0 = nd0 > bv; bv = g0 ? nd0 : bv; bk = g0 ? 2 * p     : bk;
            bool g1 = nd1 > bv; bv = g1 ? nd1 : bv; bk = g1 ? 2 * p + 1 : bk;
        }
        unsigned gi = (unsigned)(bk * NT + t);
        unsigned long long pk =
            ((unsigned long long)__float_as_uint(bv) << 32) | (unsigned)(~gi);
        pk = wave_max_key(pk);
        if (lane == 63) wkey[par][w] = pk;
        __syncthreads();
        const unsigned widx = reduce4_widx(wkey[par], lane);
        const float* cp = P + (size_t)widx * 3;
        cx = cp[0]; cy = cp[1]; cz = cp[2];
    }
}

// ---------------- generic MLP body (r12-proven; used for mlp2) ---------------
template<int NPTS, int FD, int CO, int M>
__device__ __forceinline__ void mlp_body(int bm, char* arena,
                 const float* __restrict__ pts, const float* __restrict__ feats,
                 const float* __restrict__ centers, const int* __restrict__ nidx,
                 const float* __restrict__ Wa, const float* __restrict__ ba,
                 const float* __restrict__ Wb, const float* __restrict__ bb,
                 float* __restrict__ outf) {
    constexpr int KN = KNN_;
    constexpr int GS = FD + 4;
    const int b = bm / M;
    const int t = threadIdx.x;
    float (*g)[GS]  = (float(*)[GS])arena;
    float (*h1)[CO] = (float(*)[CO])(arena + sizeof(float) * KN * GS);
    const int* nb = nidx + (size_t)bm * KN;
    const float* cen = centers + (size_t)bm * 3;
    const float cx = cen[0], cy = cen[1], cz = cen[2];
    {
        constexpr int PARTS = CO / KN;
        constexpr int CHUNK = FD / PARTS;
        const int kk = t / PARTS;
        const int q  = t % PARTS;
        const int j  = nb[kk];
        const float* f = feats + ((size_t)b * NPTS + j) * FD + q * CHUNK;
        float* gr = &g[kk][q * CHUNK];
#pragma unroll
        for (int u = 0; u < CHUNK / 4; ++u)
            *(float4*)(gr + 4 * u) = *(const float4*)(f + 4 * u);
        if (q == 0) {
            const float* p = pts + ((size_t)b * NPTS + j) * 3;
            g[kk][FD + 0] = __fsub_rn(p[0], cx);
            g[kk][FD + 1] = __fsub_rn(p[1], cy);
            g[kk][FD + 2] = __fsub_rn(p[2], cz);
            g[kk][FD + 3] = 0.f;
        }
    }
    __syncthreads();
    const int o = t;
    float acc[KN];
#pragma unroll
    for (int k = 0; k < KN; ++k) acc[k] = ba[o];
    for (int s4 = 0; s4 < FD / 4; ++s4) {
        const float w0 = Wa[(4 * s4 + 3) * CO + o];
        const float w1 = Wa[(4 * s4 + 4) * CO + o];
        const float w2 = Wa[(4 * s4 + 5) * CO + o];
        const float w3 = Wa[(4 * s4 + 6) * CO + o];
#pragma unroll
        for (int k = 0; k < KN; ++k) {
            float4 gv = *(const float4*)&g[k][4 * s4];
            acc[k] = __fmaf_rn(gv.x, w0, acc[k]);
            acc[k] = __fmaf_rn(gv.y, w1, acc[k]);
            acc[k] = __fmaf_rn(gv.z, w2, acc[k]);
            acc[k] = __fmaf_rn(gv.w, w3, acc[k]);
        }
    }
    {
        const float w0 = Wa[0 * CO + o];
        const float w1 = Wa[1 * CO + o];
        const float w2 = Wa[2 * CO + o];
#pragma unroll
        for (int k = 0; k < KN; ++k) {
            float4 gv = *(const float4*)&g[k][FD];
            acc[k] = __fmaf_rn(gv.x, w0, acc[k]);
            acc[k] = __fmaf_rn(gv.y, w1, acc[k]);
            acc[k] = __fmaf_rn(gv.z, w2, acc[k]);
        }
    }
#pragma unroll
    for (int k = 0; k < KN; ++k) h1[k][o] = fmaxf(acc[k], 0.f);
    __syncthreads();
#pragma unroll
    for (int k = 0; k < KN; ++k) acc[k] = bb[o];
    for (int s4 = 0; s4 < CO / 4; ++s4) {
        const float w0 = Wb[(4 * s4 + 0) * CO + o];
        const float w1 = Wb[(4 * s4 + 1) * CO + o];
        const float w2 = Wb[(4 * s4 + 2) * CO + o];
        const float w3 = Wb[(4 * s4 + 3) * CO + o];
#pragma unroll
        for (int k = 0; k < KN; ++k) {
            float4 hv = *(const float4*)&h1[k][4 * s4];
            acc[k] = __fmaf_rn(hv.x, w0, acc[k]);
            acc[k] = __fmaf_rn(hv.y, w1, acc[k]);
            acc[k] = __fmaf_rn(hv.z, w2, acc[k]);
            acc[k] = __fmaf_rn(hv.w, w3, acc[k]);
        }
    }
    float mx = 0.f;
#pragma unroll
    for (int k = 0; k < KN; ++k) mx = fmaxf(mx, fmaxf(acc[k], 0.f));
    outf[(size_t)bm * CO + o] = mx;
}

// ---- sa2: fps2 (0..3) | 8x(knn2-chunk | mlp2-chunk) | head (last 4) --------
__global__ void __launch_bounds__(C2_)
sa2_kernel(const float* __restrict__ centers1, const float* __restrict__ feats1,
           float* __restrict__ centers2, int* __restrict__ nidx2,
           const float* __restrict__ W2a, const float* __restrict__ b2a,
           const float* __restrict__ W2b, const float* __restrict__ b2b,
           const float* __restrict__ Wd1, const float* __restrict__ bd1,
           const float* __restrict__ Wd2, const float* __restrict__ bd2,
           float* __restrict__ feats2, float* __restrict__ outp,
           unsigned* __restrict__ flags) {
    constexpr size_t BYTES = sizeof(float) * (KNN_ * (C1_ + 4) + KNN_ * C2_); // 49664
    __shared__ alignas(16) char arena[BYTES];
    const int bid = blockIdx.x;
    const int t = threadIdx.x;
    if (bid < B_) {
        fps2_body(centers1, centers2, flags, arena);
        return;
    }
    const int kk = bid - B_;
    if (kk < 8 * 512) {
        const int c = kk >> 9;             // chunk 0..7
        const int r = kk & 511;
        const int i = r & 255;
        const int b = (i >> 6) & 3;
        const int m = c * 64 + (i & 63);
        if (r < 256) {
            // ---- knn2: waits fps2 chunk publish
            if (t == 0) {
                while (auload(F_PROG2(flags, b)) <= (unsigned)c)
                    __builtin_amdgcn_s_sleep(16);
            }
            __syncthreads();
            const float* cw = centers2 + ((size_t)b * M2_ + m) * 3;
            float cx = aload(cw + 0), cy = aload(cw + 1), cz = aload(cw + 2);
            knn_bodyT<M1_, 256>(centers1 + (size_t)b * M1_ * 3, cx, cy, cz,
                                nidx2 + ((size_t)b * M2_ + m) * KNN_, arena);
            __syncthreads();
            if (t == 0)
                __hip_atomic_fetch_add(F_K2D(flags, b, c), 1u,
                                       __ATOMIC_RELEASE, __HIP_MEMORY_SCOPE_AGENT);
            return;
        }
        // ---- mlp2: waits knn2 chunk; fence then plain loads
        if (t == 0) {
            while (auload(F_K2D(flags, b, c)) < 64u)
                __builtin_amdgcn_s_sleep(16);
        }
        __syncthreads();
        afence();
        mlp_body<M1_, C1_, C2_, M2_>((int)((size_t)b * M2_ + m), arena,
                                     centers1, feats1, centers2, nidx2,
                                     W2a, b2a, W2b, b2b, feats2);
        __syncthreads();                   // drain feats2 stores
        if (t == 0)
            __hip_atomic_fetch_add(F_M2D(flags, b), 1u,
                                   __ATOMIC_RELEASE, __HIP_MEMORY_SCOPE_AGENT);
        return;
    }
    // ---- head: waits all mlp2 of its batch
    const int b = kk - 8 * 512;
    if (t == 0) {
        while (auload(F_M2D(flags, b)) < (unsigned)M2_)
            __builtin_amdgcn_s_sleep(16);
    }
    __syncthreads();
    afence();
    float* gsh = (float*)arena;                  // 2*C2 floats
    float* hsh = (float*)(arena + 2048);         // 512 floats
    const float* F = feats2 + (size_t)b * M2_ * C2_;
    float mx = -1e30f, sm = 0.f;
    for (int r = 0; r < M2_; ++r) {
        float v = F[r * C2_ + t];
        mx = fmaxf(mx, v);
        sm += v;
    }
    gsh[t] = mx;
    gsh[C2_ + t] = sm * (1.0f / (float)M2_);
    __syncthreads();
#pragma unroll
    for (int oo = 0; oo < 2; ++oo) {
        const int o = t + oo * 256;
        float acc = bd1[o];
        for (int i = 0; i < 512; ++i)
            acc = __fmaf_rn(gsh[i], Wd1[i * 512 + o], acc);
        hsh[o] = fmaxf(acc, 0.f);
    }
    __syncthreads();
    float acc = bd2[t];
    for (int i = 0; i < 512; ++i)
        acc = __fmaf_rn(hsh[i], Wd2[i * 256 + t], acc);
    outp[b * 256 + t] = acc;
}

extern "C" void kernel_launch(void* const* d_in, const int* in_sizes, int n_in,
                              void* d_out, int out_size, void* d_ws, size_t ws_size,
                              hipStream_t stream) {
    const float* xyz = (const float*)d_in[0];
    const float* Wp  = (const float*)d_in[1];
    const float* bp  = (const float*)d_in[2];
    const float* W1a = (const float*)d_in[3];
    const float* b1a = (const float*)d_in[4];
    const float* W1b = (const float*)d_in[5];
    const float* b1b = (const float*)d_in[6];
    const float* W2a = (const float*)d_in[7];
    const float* b2a = (const float*)d_in[8];
    const float* W2b = (const float*)d_in[9];
    const float* b2b = (const float*)d_in[10];
    const float* Wd1 = (const float*)d_in[11];
    const float* bd1 = (const float*)d_in[12];
    const float* Wd2 = (const float*)d_in[13];
    const float* bd2 = (const float*)d_in[14];
    float* out = (float*)d_out;

    char* ws = (char*)d_ws;
    size_t off = 0;
    auto alloc = [&](size_t bytes) { void* p = ws + off; off += (bytes + 255) & ~(size_t)255; return p; };
    float* feats0   = (float*)alloc((size_t)B_ * N1_ * PROJ_ * 4);
    float* centers1 = (float*)alloc((size_t)B_ * M1_ * 3 * 4);
    int*   nidx1    = (int*)  alloc((size_t)B_ * M1_ * KNN_ * 4);
    float* feats1   = (float*)alloc((size_t)B_ * M1_ * C1_ * 4);
    float* centers2 = (float*)alloc((size_t)B_ * M2_ * 3 * 4);
    int*   nidx2    = (int*)  alloc((size_t)B_ * M2_ * KNN_ * 4);
    float* feats2   = (float*)alloc((size_t)B_ * M2_ * C2_ * 4);
    unsigned* flags = (unsigned*)alloc(16384);
    float* sx       = (float*)alloc((size_t)B_ * N1_ * 4);
    float* sy       = (float*)alloc((size_t)B_ * N1_ * 4);
    float* sz       = (float*)alloc((size_t)B_ * N1_ * 4);
    float* sp       = (float*)alloc((size_t)B_ * N1_ * 3 * 4);
    (void)in_sizes; (void)n_in; (void)out_size; (void)ws_size;

    // zero all pipeline flags each launch (graph replays must not see stale)
    hipMemsetAsync(flags, 0, 16384, stream);

    // 0: x-sort for slab-pruned FPS (~25 us, 4 blocks)
    sortx_kernel<<<dim3(B_), dim3(1024), 0, stream>>>(xyz, sx, sy, sz, sp);
    // 1: fps1 (0..3) + proj (8192) + 32 x (knn1 256 | mlp1 256) interleaved
    mega1_kernel<<<dim3(B_ + PROJ_BLKS_ + TAIL_BLKS_), dim3(512), 0, stream>>>(
        xyz, sx, sy, sz, sp, Wp, bp, W1a, b1a, W1b, b1b,
        feats0, centers1, nidx1, feats1, flags);
    // 2: fps2 (0..3) + 8 x (knn2 256 | mlp2 256) + head (4)
    sa2_kernel<<<dim3(B_ + 8 * 512 + B_), dim3(C2_), 0, stream>>>(
        centers1, feats1, centers2, nidx2, W2a, b2a, W2b, b2b,
        Wd1, bd1, Wd2, bd2, feats2, out, flags);
}